// Round 5
// baseline (264.946 us; speedup 1.0000x reference)
//
#include <hip/hip_runtime.h>

typedef unsigned short u16;
typedef unsigned int u32;
typedef __bf16 bf16x8 __attribute__((ext_vector_type(8)));
typedef float f32x4 __attribute__((ext_vector_type(4)));

#define S_LEN 1536
#define DIM 2880
#define NQH 64
#define NKVH 8
#define HD 64
#define QKV_N 5120
#define QDIM 4096
#define KVDIM 512
#define WIN 128
#define SM_SCALE 0.125f

__device__ __forceinline__ u16 f2bf(float f) {
  union { float f; u32 u; } a; a.f = f;
  u32 u = a.u;
  u32 lsb = (u >> 16) & 1;
  u += 0x7fffu + lsb;
  return (u16)(u >> 16);
}
__device__ __forceinline__ u32 pk2bf(float a, float b) {
  return (u32)f2bf(a) | ((u32)f2bf(b) << 16);
}

#define GLOAD16(g, l) __builtin_amdgcn_global_load_lds( \
    (const __attribute__((address_space(1))) u32*)(g), \
    (__attribute__((address_space(3))) u32*)(l), 16, 0, 0)

// ---------------- YaRN rope tables ----------------
__global__ void rope_tables(float* __restrict__ cosT, float* __restrict__ sinT) {
  int idx = blockIdx.x * blockDim.x + threadIdx.x;
  if (idx >= S_LEN * 32) return;
  int s = idx >> 5, d = idx & 31;
  const double TWO_PI = 6.283185307179586;
  double freq = pow(150000.0, (double)d / 32.0);
  double conc = 0.1 * log(32.0) + 1.0;
  double lb = log(150000.0);
  double low = 32.0 * log(4096.0 / (32.0 * TWO_PI)) / lb;
  double high = 32.0 * log(4096.0 / (1.0 * TWO_PI)) / lb;
  double interp = 1.0 / (32.0 * freq), extra = 1.0 / freq;
  double ramp = ((double)d - low) / (high - low);
  ramp = ramp < 0.0 ? 0.0 : (ramp > 1.0 ? 1.0 : ramp);
  double maskv = 1.0 - ramp;
  double invf = interp * (1.0 - maskv) + extra * maskv;
  double ang = (double)s * invf;
  cosT[idx] = (float)(cos(ang) * conc);
  sinT[idx] = (float)(sin(ang) * conc);
}

// ---------------- RMSNorm -> bf16 ----------------
__global__ __launch_bounds__(256) void rmsnorm_bf16(
    const float* __restrict__ x, const float* __restrict__ wgt,
    u16* __restrict__ th) {
  int row = blockIdx.x;
  const float* xr = x + (size_t)row * DIM;
  float ss = 0.f;
  for (int i = threadIdx.x; i < DIM / 4; i += 256) {
    float4 v = *(const float4*)&xr[i * 4];
    ss += v.x * v.x + v.y * v.y + v.z * v.z + v.w * v.w;
  }
  for (int m = 32; m >= 1; m >>= 1) ss += __shfl_xor(ss, m);
  __shared__ float red[4];
  int lane = threadIdx.x & 63, w = threadIdx.x >> 6;
  if (lane == 0) red[w] = ss;
  __syncthreads();
  float tot = red[0] + red[1] + red[2] + red[3];
  float scale = rsqrtf(tot / (float)DIM + 1e-5f);
  for (int i = threadIdx.x; i < DIM / 4; i += 256) {
    float4 v = *(const float4*)&xr[i * 4];
    float4 g = *(const float4*)&wgt[i * 4];
    ushort4 hi;
    hi.x = f2bf(v.x * scale * g.x);
    hi.y = f2bf(v.y * scale * g.y);
    hi.z = f2bf(v.z * scale * g.z);
    hi.w = f2bf(v.w * scale * g.w);
    *(ushort4*)&th[(size_t)row * DIM + i * 4] = hi;
  }
}

// ---------------- fp32 -> bf16 convert, two arrays in one launch ----------------
__global__ __launch_bounds__(256) void conv2(
    const float* __restrict__ s1, u16* __restrict__ d1, long n1,
    const float* __restrict__ s2, u16* __restrict__ d2, long n2) {
  long idx = (long)blockIdx.x * 256 + threadIdx.x;
  const float* src; u16* dst; long i;
  if (idx < n1) { src = s1; dst = d1; i = idx; }
  else if (idx < n1 + n2) { src = s2; dst = d2; i = idx - n1; }
  else return;
  float4 v = *(const float4*)&src[i * 4];
  ushort4 h;
  h.x = f2bf(v.x); h.y = f2bf(v.y); h.z = f2bf(v.z); h.w = f2bf(v.w);
  *(ushort4*)&dst[i * 4] = h;
}

// ================= 128x256 8-phase GEMM machinery (v6, m201-style) =================
// R0-R4 lesson: every 2-phase schedule pins at ~500 TF (m233 stall). This is the
// m201 per-phase interleave: 512 thr = 8 waves (2M x 4N), wave tile 64x64,
// acc 4x4, BK=64 (2 k32 subtiles). Per K-tile: 4 phases, each
//   {stage-issue 2 gload_lds || ds_read subtile || setprio(1) 8 MFMA setprio(0)}
// Quadrant order (0,0)(0,1)(1,1)(1,0) reuses a/b fragments between phases.
// TRIPLE-buffered LDS (A 3x16KB + B 3x32KB = 144KB, 1 block/CU), stage depth =
// 2 K-tiles, ONE counted vmcnt(6) + barrier per K-tile (never 0 mid-loop),
// barriers after ph0/ph1/ph2 (top-of-iter barrier covers ph3).
// Buffer safety: iter tt reads buf tt%3, stages (tt+2)%3; last reads of a
// buffer complete (lgkm before MFMA) before the wave reaches the next top
// barrier, which precedes its overwrite.
// Slot swizzle (verified conflict-free): slot p -> row p>>2, global k-slot
// (p&3)^((p>>3)&3); read column lk8^(((lr>>1)&3)<<3).

// ---------------- QKV GEMM with fused bias+RoPE+bf16+V-transpose epilogue ----------------
__global__ __launch_bounds__(512, 2) void gemm_rope(
    const u16* __restrict__ A, const u16* __restrict__ B,
    const float* __restrict__ bias,
    const float* __restrict__ cosT, const float* __restrict__ sinT,
    u16* __restrict__ Qb, u16* __restrict__ Kb, u16* __restrict__ Vt) {
  __shared__ u16 As[3 * 8192];    // [buf][ks][128*32]
  __shared__ u16 Bs[3 * 16384];   // [buf][ks][256*32]
  const int K = DIM;
  const int t = threadIdx.x;           // 0..511
  const int lane = t & 63, wid = t >> 6;
  const int wm = wid >> 2, wn = wid & 3;

  const int nby = gridDim.y;  // M tiles (12)
  const int nwg = gridDim.x * nby;   // 240
  int orig = blockIdx.x * nby + blockIdx.y;
  {
    int q = nwg >> 3, r = nwg & 7;
    int xcd = orig & 7, i = orig >> 3;
    orig = (xcd < r ? xcd * (q + 1) : r * (q + 1) + (xcd - r) * q) + i;
  }
  const int m0 = (orig % nby) * 128, n0 = (orig / nby) * 256;

  const int wr = wm * 64, wc = wn * 64;
  const int lr = lane & 15, lk8 = (lane >> 4) * 8;
  const int lcol = lk8 ^ (((lr >> 1) & 3) << 3);
  const int g4 = (lane >> 4) * 4;
  f32x4 acc[4][4] = {};

  const int swz = ((t & 3) ^ ((t >> 3) & 3)) * 8;
  const size_t ga  = (size_t)(m0 + (t >> 2)) * K + swz;
  const size_t gb0 = (size_t)(n0 + (t >> 2)) * K + swz;
  const size_t gb1 = (size_t)(n0 + 128 + (t >> 2)) * K + swz;

  auto STAGE_A = [&](int buf, int k0) {
    GLOAD16(A + ga + k0,      &As[buf * 8192 + t * 8]);
    GLOAD16(A + ga + k0 + 32, &As[buf * 8192 + 4096 + t * 8]);
  };
  auto STAGE_B0 = [&](int buf, int k0) {
    GLOAD16(B + gb0 + k0,      &Bs[buf * 16384 + t * 8]);
    GLOAD16(B + gb0 + k0 + 32, &Bs[buf * 16384 + 8192 + t * 8]);
  };
  auto STAGE_B1 = [&](int buf, int k0) {
    GLOAD16(B + gb1 + k0,      &Bs[buf * 16384 + 4096 + t * 8]);
    GLOAD16(B + gb1 + k0 + 32, &Bs[buf * 16384 + 8192 + 4096 + t * 8]);
  };

  const int nkt = K / 64;   // 45
  STAGE_A(0, 0);  STAGE_B0(0, 0);  STAGE_B1(0, 0);
  STAGE_A(1, 64); STAGE_B0(1, 64); STAGE_B1(1, 64);

  bf16x8 af[2][4], bf[2][4];
  for (int tt = 0; tt < nkt; ++tt) {
    const int b0 = tt % 3;
    const int b2 = (tt + 2) % 3;
    const int k2 = (tt + 2) * 64;
    const bool pf = (tt + 2) < nkt;
    if (tt + 1 < nkt) { asm volatile("s_waitcnt vmcnt(6)" ::: "memory"); }
    else              { asm volatile("s_waitcnt vmcnt(0)" ::: "memory"); }
    __builtin_amdgcn_s_barrier();
    __builtin_amdgcn_sched_barrier(0);
    const u16* as_ = &As[b0 * 8192];
    const u16* bs_ = &Bs[b0 * 16384];
    // ---- ph0: stage A(tt+2); read a01,b01; MFMA quad(0,0)
    if (pf) STAGE_A(b2, k2);
#pragma unroll
    for (int ks = 0; ks < 2; ++ks) {
#pragma unroll
      for (int i = 0; i < 2; ++i) af[ks][i] = *(const bf16x8*)&as_[ks * 4096 + (wr + i * 16 + lr) * 32 + lcol];
#pragma unroll
      for (int j = 0; j < 2; ++j) bf[ks][j] = *(const bf16x8*)&bs_[ks * 8192 + (wc + j * 16 + lr) * 32 + lcol];
    }
    __builtin_amdgcn_s_setprio(1);
#pragma unroll
    for (int ks = 0; ks < 2; ++ks)
#pragma unroll
      for (int i = 0; i < 2; ++i)
#pragma unroll
        for (int j = 0; j < 2; ++j)
          acc[i][j] = __builtin_amdgcn_mfma_f32_16x16x32_bf16(af[ks][i], bf[ks][j], acc[i][j], 0, 0, 0);
    __builtin_amdgcn_s_setprio(0);
    __builtin_amdgcn_sched_barrier(0);
    __builtin_amdgcn_s_barrier();
    __builtin_amdgcn_sched_barrier(0);
    // ---- ph1: stage B0(tt+2); read b23; MFMA quad(0,1)
    if (pf) STAGE_B0(b2, k2);
#pragma unroll
    for (int ks = 0; ks < 2; ++ks)
#pragma unroll
      for (int j = 2; j < 4; ++j) bf[ks][j] = *(const bf16x8*)&bs_[ks * 8192 + (wc + j * 16 + lr) * 32 + lcol];
    __builtin_amdgcn_s_setprio(1);
#pragma unroll
    for (int ks = 0; ks < 2; ++ks)
#pragma unroll
      for (int i = 0; i < 2; ++i)
#pragma unroll
        for (int j = 2; j < 4; ++j)
          acc[i][j] = __builtin_amdgcn_mfma_f32_16x16x32_bf16(af[ks][i], bf[ks][j], acc[i][j], 0, 0, 0);
    __builtin_amdgcn_s_setprio(0);
    __builtin_amdgcn_sched_barrier(0);
    __builtin_amdgcn_s_barrier();
    __builtin_amdgcn_sched_barrier(0);
    // ---- ph2: stage B1(tt+2); read a23; MFMA quad(1,1)
    if (pf) STAGE_B1(b2, k2);
#pragma unroll
    for (int ks = 0; ks < 2; ++ks)
#pragma unroll
      for (int i = 2; i < 4; ++i) af[ks][i] = *(const bf16x8*)&as_[ks * 4096 + (wr + i * 16 + lr) * 32 + lcol];
    __builtin_amdgcn_s_setprio(1);
#pragma unroll
    for (int ks = 0; ks < 2; ++ks)
#pragma unroll
      for (int i = 2; i < 4; ++i)
#pragma unroll
        for (int j = 2; j < 4; ++j)
          acc[i][j] = __builtin_amdgcn_mfma_f32_16x16x32_bf16(af[ks][i], bf[ks][j], acc[i][j], 0, 0, 0);
    __builtin_amdgcn_s_setprio(0);
    __builtin_amdgcn_sched_barrier(0);
    __builtin_amdgcn_s_barrier();
    __builtin_amdgcn_sched_barrier(0);
    // ---- ph3: read b01 (again); MFMA quad(1,0); no trailing barrier
#pragma unroll
    for (int ks = 0; ks < 2; ++ks)
#pragma unroll
      for (int j = 0; j < 2; ++j) bf[ks][j] = *(const bf16x8*)&bs_[ks * 8192 + (wc + j * 16 + lr) * 32 + lcol];
    __builtin_amdgcn_s_setprio(1);
#pragma unroll
    for (int ks = 0; ks < 2; ++ks)
#pragma unroll
      for (int i = 2; i < 4; ++i)
#pragma unroll
        for (int j = 0; j < 2; ++j)
          acc[i][j] = __builtin_amdgcn_mfma_f32_16x16x32_bf16(af[ks][i], bf[ks][j], acc[i][j], 0, 0, 0);
    __builtin_amdgcn_s_setprio(0);
  }

  if (n0 < 4608) {  // q or k region: bias + rope + bf16 (tile fully in one region: boundaries %256==0)
    const bool isQ = (n0 < 4096);
    const float sc = isQ ? SM_SCALE : 1.0f;
#pragma unroll
    for (int i = 0; i < 4; ++i) {
      const int row = m0 + wr + i * 16 + g4;
#pragma unroll
      for (int j = 0; j < 2; ++j) {
        const int col = n0 + wc + j * 16 + lr;
        const int d = j * 16 + lr;
        const float b1 = bias[col], b2v = bias[col + 32];
#pragma unroll
        for (int r = 0; r < 4; ++r) {
          const float c = cosT[(row + r) * 32 + d];
          const float s = sinT[(row + r) * 32 + d];
          const float x1 = acc[i][j][r] + b1;
          const float x2 = acc[i][j + 2][r] + b2v;
          const float o1 = (x1 * c - x2 * s) * sc;
          const float o2 = (x2 * c + x1 * s) * sc;
          if (isQ) {
            Qb[(size_t)(row + r) * QDIM + col] = f2bf(o1);
            Qb[(size_t)(row + r) * QDIM + col + 32] = f2bf(o2);
          } else {
            Kb[(size_t)(row + r) * KVDIM + (col - 4096)] = f2bf(o1);
            Kb[(size_t)(row + r) * KVDIM + (col - 4096) + 32] = f2bf(o2);
          }
        }
      }
    }
  } else {  // v region: bias + bf16, transposed store Vt[vcol][s]
#pragma unroll
    for (int i = 0; i < 4; ++i) {
      const int rowb = m0 + wr + i * 16 + g4;
#pragma unroll
      for (int j = 0; j < 4; ++j) {
        const int col = n0 + wc + j * 16 + lr;
        const float bb = bias[col];
        ushort4 pk;
        pk.x = f2bf(acc[i][j][0] + bb);
        pk.y = f2bf(acc[i][j][1] + bb);
        pk.z = f2bf(acc[i][j][2] + bb);
        pk.w = f2bf(acc[i][j][3] + bb);
        *(ushort4*)&Vt[(size_t)(col - 4608) * S_LEN + rowb] = pk;
      }
    }
  }
}

// ---------------- out GEMM: C = A @ B^T + bias (fp32 out, ragged N) ----------------
__global__ __launch_bounds__(512, 2) void gemm_bt(
    const u16* __restrict__ A, const u16* __restrict__ B,
    const float* __restrict__ bias, float* __restrict__ C,
    int M, int N, int K) {
  __shared__ u16 As[3 * 8192];
  __shared__ u16 Bs[3 * 16384];
  const int t = threadIdx.x;
  const int lane = t & 63, wid = t >> 6;
  const int wm = wid >> 2, wn = wid & 3;

  const int nby = gridDim.y;  // 12
  const int nwg = gridDim.x * nby;  // 144
  int orig = blockIdx.x * nby + blockIdx.y;
  {
    int q = nwg >> 3, r = nwg & 7;
    int xcd = orig & 7, i = orig >> 3;
    orig = (xcd < r ? xcd * (q + 1) : r * (q + 1) + (xcd - r) * q) + i;
  }
  const int m0 = (orig % nby) * 128, n0 = (orig / nby) * 256;

  const int wr = wm * 64, wc = wn * 64;
  const int lr = lane & 15, lk8 = (lane >> 4) * 8;
  const int lcol = lk8 ^ (((lr >> 1) & 3) << 3);
  const int g4 = (lane >> 4) * 4;
  f32x4 acc[4][4] = {};

  const int swz = ((t & 3) ^ ((t >> 3) & 3)) * 8;
  int rB0 = n0 + (t >> 2);       if (rB0 > N - 1) rB0 = N - 1;
  int rB1 = n0 + 128 + (t >> 2); if (rB1 > N - 1) rB1 = N - 1;
  const size_t ga  = (size_t)(m0 + (t >> 2)) * K + swz;
  const size_t gb0 = (size_t)rB0 * K + swz;
  const size_t gb1 = (size_t)rB1 * K + swz;

  auto STAGE_A = [&](int buf, int k0) {
    GLOAD16(A + ga + k0,      &As[buf * 8192 + t * 8]);
    GLOAD16(A + ga + k0 + 32, &As[buf * 8192 + 4096 + t * 8]);
  };
  auto STAGE_B0 = [&](int buf, int k0) {
    GLOAD16(B + gb0 + k0,      &Bs[buf * 16384 + t * 8]);
    GLOAD16(B + gb0 + k0 + 32, &Bs[buf * 16384 + 8192 + t * 8]);
  };
  auto STAGE_B1 = [&](int buf, int k0) {
    GLOAD16(B + gb1 + k0,      &Bs[buf * 16384 + 4096 + t * 8]);
    GLOAD16(B + gb1 + k0 + 32, &Bs[buf * 16384 + 8192 + 4096 + t * 8]);
  };

  const int nkt = K / 64;   // 64
  STAGE_A(0, 0);  STAGE_B0(0, 0);  STAGE_B1(0, 0);
  STAGE_A(1, 64); STAGE_B0(1, 64); STAGE_B1(1, 64);

  bf16x8 af[2][4], bf[2][4];
  for (int tt = 0; tt < nkt; ++tt) {
    const int b0 = tt % 3;
    const int b2 = (tt + 2) % 3;
    const int k2 = (tt + 2) * 64;
    const bool pf = (tt + 2) < nkt;
    if (tt + 1 < nkt) { asm volatile("s_waitcnt vmcnt(6)" ::: "memory"); }
    else              { asm volatile("s_waitcnt vmcnt(0)" ::: "memory"); }
    __builtin_amdgcn_s_barrier();
    __builtin_amdgcn_sched_barrier(0);
    const u16* as_ = &As[b0 * 8192];
    const u16* bs_ = &Bs[b0 * 16384];
    if (pf) STAGE_A(b2, k2);
#pragma unroll
    for (int ks = 0; ks < 2; ++ks) {
#pragma unroll
      for (int i = 0; i < 2; ++i) af[ks][i] = *(const bf16x8*)&as_[ks * 4096 + (wr + i * 16 + lr) * 32 + lcol];
#pragma unroll
      for (int j = 0; j < 2; ++j) bf[ks][j] = *(const bf16x8*)&bs_[ks * 8192 + (wc + j * 16 + lr) * 32 + lcol];
    }
    __builtin_amdgcn_s_setprio(1);
#pragma unroll
    for (int ks = 0; ks < 2; ++ks)
#pragma unroll
      for (int i = 0; i < 2; ++i)
#pragma unroll
        for (int j = 0; j < 2; ++j)
          acc[i][j] = __builtin_amdgcn_mfma_f32_16x16x32_bf16(af[ks][i], bf[ks][j], acc[i][j], 0, 0, 0);
    __builtin_amdgcn_s_setprio(0);
    __builtin_amdgcn_sched_barrier(0);
    __builtin_amdgcn_s_barrier();
    __builtin_amdgcn_sched_barrier(0);
    if (pf) STAGE_B0(b2, k2);
#pragma unroll
    for (int ks = 0; ks < 2; ++ks)
#pragma unroll
      for (int j = 2; j < 4; ++j) bf[ks][j] = *(const bf16x8*)&bs_[ks * 8192 + (wc + j * 16 + lr) * 32 + lcol];
    __builtin_amdgcn_s_setprio(1);
#pragma unroll
    for (int ks = 0; ks < 2; ++ks)
#pragma unroll
      for (int i = 0; i < 2; ++i)
#pragma unroll
        for (int j = 2; j < 4; ++j)
          acc[i][j] = __builtin_amdgcn_mfma_f32_16x16x32_bf16(af[ks][i], bf[ks][j], acc[i][j], 0, 0, 0);
    __builtin_amdgcn_s_setprio(0);
    __builtin_amdgcn_sched_barrier(0);
    __builtin_amdgcn_s_barrier();
    __builtin_amdgcn_sched_barrier(0);
    if (pf) STAGE_B1(b2, k2);
#pragma unroll
    for (int ks = 0; ks < 2; ++ks)
#pragma unroll
      for (int i = 2; i < 4; ++i) af[ks][i] = *(const bf16x8*)&as_[ks * 4096 + (wr + i * 16 + lr) * 32 + lcol];
    __builtin_amdgcn_s_setprio(1);
#pragma unroll
    for (int ks = 0; ks < 2; ++ks)
#pragma unroll
      for (int i = 2; i < 4; ++i)
#pragma unroll
        for (int j = 2; j < 4; ++j)
          acc[i][j] = __builtin_amdgcn_mfma_f32_16x16x32_bf16(af[ks][i], bf[ks][j], acc[i][j], 0, 0, 0);
    __builtin_amdgcn_s_setprio(0);
    __builtin_amdgcn_sched_barrier(0);
    __builtin_amdgcn_s_barrier();
    __builtin_amdgcn_sched_barrier(0);
#pragma unroll
    for (int ks = 0; ks < 2; ++ks)
#pragma unroll
      for (int j = 0; j < 2; ++j) bf[ks][j] = *(const bf16x8*)&bs_[ks * 8192 + (wc + j * 16 + lr) * 32 + lcol];
    __builtin_amdgcn_s_setprio(1);
#pragma unroll
    for (int ks = 0; ks < 2; ++ks)
#pragma unroll
      for (int i = 2; i < 4; ++i)
#pragma unroll
        for (int j = 0; j < 2; ++j)
          acc[i][j] = __builtin_amdgcn_mfma_f32_16x16x32_bf16(af[ks][i], bf[ks][j], acc[i][j], 0, 0, 0);
    __builtin_amdgcn_s_setprio(0);
  }

#pragma unroll
  for (int i = 0; i < 4; ++i) {
    const int row = m0 + wr + i * 16 + g4;
#pragma unroll
    for (int j = 0; j < 4; ++j) {
      const int col = n0 + wc + j * 16 + lr;
      if (col < N) {
        const float bb = bias[col];
#pragma unroll
        for (int r = 0; r < 4; ++r)
          C[(size_t)(row + r) * N + col] = acc[i][j][r] + bb;
      }
    }
  }
}

// ---------------- LDS-free fused attention (swapped-operand MFMA) ----------------
__global__ __launch_bounds__(256) void attn2(
    const u16* __restrict__ Q, const u16* __restrict__ Kb, const u16* __restrict__ Vt,
    const float* __restrict__ sinks, u16* __restrict__ O) {
  const int h = blockIdx.x;
  const int kh = h >> 3;
  const int wid = threadIdx.x >> 6;
  const int lane = threadIdx.x & 63;
  const int q0 = blockIdx.y * 128 + wid * 32;
  const int lr = lane & 15;
  const int g = lane >> 4;

  bf16x8 bq[2][2];
#pragma unroll
  for (int qf = 0; qf < 2; ++qf)
#pragma unroll
    for (int kc = 0; kc < 2; ++kc)
      bq[qf][kc] = *(const bf16x8*)&Q[(size_t)(q0 + qf * 16 + lr) * QDIM + h * HD + kc * 32 + g * 8];

  f32x4 o[2][4] = {};
  float m_s[2] = {-1e30f, -1e30f};
  float l_s[2] = {0.f, 0.f};

  int js = q0 - 128; if (js < 0) js = 0;

  for (int j0 = js; j0 <= q0; j0 += 32) {
    bf16x8 ak[2][2];
#pragma unroll
    for (int jf = 0; jf < 2; ++jf)
#pragma unroll
      for (int kc = 0; kc < 2; ++kc)
        ak[jf][kc] = *(const bf16x8*)&Kb[(size_t)(j0 + jf * 16 + lr) * KVDIM + kh * HD + kc * 32 + g * 8];

    f32x4 st[2][2] = {};
#pragma unroll
    for (int jf = 0; jf < 2; ++jf)
#pragma unroll
      for (int qf = 0; qf < 2; ++qf) {
        st[jf][qf] = __builtin_amdgcn_mfma_f32_16x16x32_bf16(ak[jf][0], bq[qf][0], st[jf][qf], 0, 0, 0);
        st[jf][qf] = __builtin_amdgcn_mfma_f32_16x16x32_bf16(ak[jf][1], bq[qf][1], st[jf][qf], 0, 0, 0);
      }

    float pv[2][2][4];
    float tmax[2] = {-1e30f, -1e30f};
#pragma unroll
    for (int jf = 0; jf < 2; ++jf)
#pragma unroll
      for (int qf = 0; qf < 2; ++qf)
#pragma unroll
        for (int r = 0; r < 4; ++r) {
          int jv = j0 + jf * 16 + 4 * g + r;
          int qq = q0 + qf * 16 + lr;
          float sc = st[jf][qf][r];
          bool ok = (jv <= qq) && (qq - jv < WIN);
          sc = ok ? sc : -1e30f;
          pv[jf][qf][r] = sc;
          tmax[qf] = fmaxf(tmax[qf], sc);
        }
#pragma unroll
    for (int qf = 0; qf < 2; ++qf) {
      float tm = tmax[qf];
      tm = fmaxf(tm, __shfl_xor(tm, 16));
      tm = fmaxf(tm, __shfl_xor(tm, 32));
      const float mo = m_s[qf];
      const float mn = fmaxf(mo, tm);
      const float esc = __expf(mo - mn);
      float ps = 0.f;
#pragma unroll
      for (int jf = 0; jf < 2; ++jf)
#pragma unroll
        for (int r = 0; r < 4; ++r) {
          float sv = pv[jf][qf][r];
          float e = __expf(sv - mn);
          e = (sv <= -1e29f) ? 0.f : e;
          pv[jf][qf][r] = e;
          ps += e;
        }
      ps += __shfl_xor(ps, 16);
      ps += __shfl_xor(ps, 32);
      l_s[qf] = l_s[qf] * esc + ps;
      m_s[qf] = mn;
#pragma unroll
      for (int df = 0; df < 4; ++df) o[qf][df] *= esc;
    }

    bf16x8 pb[2];
    const int srcA = lr + ((g & 1) ? 32 : 0);
    const int srcB = srcA + 16;
    const bool hi_half = (g >= 2);
#pragma unroll
    for (int qf = 0; qf < 2; ++qf) {
      u32 w0a = pk2bf(pv[0][qf][0], pv[0][qf][1]);
      u32 w1a = pk2bf(pv[0][qf][2], pv[0][qf][3]);
      u32 w0b = pk2bf(pv[1][qf][0], pv[1][qf][1]);
      u32 w1b = pk2bf(pv[1][qf][2], pv[1][qf][3]);
      u32 a0 = (u32)__shfl((int)w0a, srcA, 64);
      u32 a1 = (u32)__shfl((int)w1a, srcA, 64);
      u32 a2 = (u32)__shfl((int)w0a, srcB, 64);
      u32 a3 = (u32)__shfl((int)w1a, srcB, 64);
      u32 b0 = (u32)__shfl((int)w0b, srcA, 64);
      u32 b1 = (u32)__shfl((int)w1b, srcA, 64);
      u32 b2 = (u32)__shfl((int)w0b, srcB, 64);
      u32 b3 = (u32)__shfl((int)w1b, srcB, 64);
      union { u32 d[4]; bf16x8 v; } u_;
      u_.d[0] = hi_half ? b0 : a0;
      u_.d[1] = hi_half ? b1 : a1;
      u_.d[2] = hi_half ? b2 : a2;
      u_.d[3] = hi_half ? b3 : a3;
      pb[qf] = u_.v;
    }

    bf16x8 av[4];
#pragma unroll
    for (int df = 0; df < 4; ++df)
      av[df] = *(const bf16x8*)&Vt[((size_t)kh * HD + df * 16 + lr) * S_LEN + j0 + g * 8];

#pragma unroll
    for (int qf = 0; qf < 2; ++qf)
#pragma unroll
      for (int df = 0; df < 4; ++df)
        o[qf][df] = __builtin_amdgcn_mfma_f32_16x16x32_bf16(av[df], pb[qf], o[qf][df], 0, 0, 0);
  }

  const float snk = sinks[h];
#pragma unroll
  for (int qf = 0; qf < 2; ++qf) {
    const float mo = m_s[qf];
    const float Mx = fmaxf(mo, snk);
    const float den = l_s[qf] * __expf(mo - Mx) + __expf(snk - Mx);
    const float osc = __expf(mo - Mx) / den;
    const int row = q0 + qf * 16 + lr;
#pragma unroll
    for (int df = 0; df < 4; ++df) {
      ushort4 pk;
      pk.x = f2bf(o[qf][df][0] * osc);
      pk.y = f2bf(o[qf][df][1] * osc);
      pk.z = f2bf(o[qf][df][2] * osc);
      pk.w = f2bf(o[qf][df][3] * osc);
      *(ushort4*)&O[(size_t)row * QDIM + h * HD + df * 16 + 4 * g] = pk;
    }
  }
}

// ---------------- launcher ----------------
extern "C" void kernel_launch(void* const* d_in, const int* in_sizes, int n_in,
                              void* d_out, int out_size, void* d_ws, size_t ws_size,
                              hipStream_t stream) {
  const float* x      = (const float*)d_in[0];
  const float* sinks  = (const float*)d_in[1];
  const float* norm_w = (const float*)d_in[2];
  const float* qkv_w  = (const float*)d_in[3];
  const float* qkv_b  = (const float*)d_in[4];
  const float* out_w  = (const float*)d_in[5];
  const float* out_b  = (const float*)d_in[6];
  float* out = (float*)d_out;

  char* ws = (char*)d_ws;
  size_t off = 0;
  auto take = [&](size_t bytes) -> void* {
    void* r = ws + off;
    off += (bytes + 255) & ~(size_t)255;
    return r;
  };
  float* cosT = (float*)take((size_t)S_LEN * 32 * 4);
  float* sinT = (float*)take((size_t)S_LEN * 32 * 4);
  u16* th  = (u16*)take((size_t)S_LEN * DIM * 2);
  u16* wh  = (u16*)take((size_t)QKV_N * DIM * 2);
  u16* ow  = (u16*)take((size_t)DIM * QDIM * 2);
  u16* Qb  = (u16*)take((size_t)S_LEN * QDIM * 2);
  u16* Kb  = (u16*)take((size_t)S_LEN * KVDIM * 2);
  u16* Vt  = (u16*)take((size_t)S_LEN * KVDIM * 2);
  u16* Ab  = (u16*)take((size_t)S_LEN * QDIM * 2);

  const long n1 = (long)QKV_N * DIM / 4;
  const long n2 = (long)DIM * QDIM / 4;

  rope_tables<<<(S_LEN * 32 + 255) / 256, 256, 0, stream>>>(cosT, sinT);
  rmsnorm_bf16<<<S_LEN, 256, 0, stream>>>(x, norm_w, th);
  conv2<<<(int)((n1 + n2 + 255) / 256), 256, 0, stream>>>(qkv_w, wh, n1, out_w, ow, n2);
  gemm_rope<<<dim3(QKV_N / 256, S_LEN / 128), 512, 0, stream>>>(
      th, wh, qkv_b, cosT, sinT, Qb, Kb, Vt);
  attn2<<<dim3(NQH, S_LEN / 128), 256, 0, stream>>>(Qb, Kb, Vt, sinks, Ab);
  gemm_bt<<<dim3((DIM + 255) / 256, S_LEN / 128), 512, 0, stream>>>(
      Ab, ow, out_b, out, S_LEN, DIM, QDIM);
}

// Round 6
// 242.515 us; speedup vs baseline: 1.0925x; 1.0925x over previous
//
#include <hip/hip_runtime.h>

typedef unsigned short u16;
typedef unsigned int u32;
typedef __bf16 bf16x8 __attribute__((ext_vector_type(8)));
typedef float f32x4 __attribute__((ext_vector_type(4)));

#define S_LEN 1536
#define DIM 2880
#define NQH 64
#define NKVH 8
#define HD 64
#define QKV_N 5120
#define QDIM 4096
#define KVDIM 512
#define WIN 128
#define SM_SCALE 0.125f

__device__ __forceinline__ u16 f2bf(float f) {
  union { float f; u32 u; } a; a.f = f;
  u32 u = a.u;
  u32 lsb = (u >> 16) & 1;
  u += 0x7fffu + lsb;
  return (u16)(u >> 16);
}
__device__ __forceinline__ u32 pk2bf(float a, float b) {
  return (u32)f2bf(a) | ((u32)f2bf(b) << 16);
}

#define GLOAD16(g, l) __builtin_amdgcn_global_load_lds( \
    (const __attribute__((address_space(1))) u32*)(g), \
    (__attribute__((address_space(3))) u32*)(l), 16, 0, 0)

// ---------------- YaRN rope tables ----------------
__global__ void rope_tables(float* __restrict__ cosT, float* __restrict__ sinT) {
  int idx = blockIdx.x * blockDim.x + threadIdx.x;
  if (idx >= S_LEN * 32) return;
  int s = idx >> 5, d = idx & 31;
  const double TWO_PI = 6.283185307179586;
  double freq = pow(150000.0, (double)d / 32.0);
  double conc = 0.1 * log(32.0) + 1.0;
  double lb = log(150000.0);
  double low = 32.0 * log(4096.0 / (32.0 * TWO_PI)) / lb;
  double high = 32.0 * log(4096.0 / (1.0 * TWO_PI)) / lb;
  double interp = 1.0 / (32.0 * freq), extra = 1.0 / freq;
  double ramp = ((double)d - low) / (high - low);
  ramp = ramp < 0.0 ? 0.0 : (ramp > 1.0 ? 1.0 : ramp);
  double maskv = 1.0 - ramp;
  double invf = interp * (1.0 - maskv) + extra * maskv;
  double ang = (double)s * invf;
  cosT[idx] = (float)(cos(ang) * conc);
  sinT[idx] = (float)(sin(ang) * conc);
}

// ---------------- RMSNorm -> bf16 ----------------
__global__ __launch_bounds__(256) void rmsnorm_bf16(
    const float* __restrict__ x, const float* __restrict__ wgt,
    u16* __restrict__ th) {
  int row = blockIdx.x;
  const float* xr = x + (size_t)row * DIM;
  float ss = 0.f;
  for (int i = threadIdx.x; i < DIM / 4; i += 256) {
    float4 v = *(const float4*)&xr[i * 4];
    ss += v.x * v.x + v.y * v.y + v.z * v.z + v.w * v.w;
  }
  for (int m = 32; m >= 1; m >>= 1) ss += __shfl_xor(ss, m);
  __shared__ float red[4];
  int lane = threadIdx.x & 63, w = threadIdx.x >> 6;
  if (lane == 0) red[w] = ss;
  __syncthreads();
  float tot = red[0] + red[1] + red[2] + red[3];
  float scale = rsqrtf(tot / (float)DIM + 1e-5f);
  for (int i = threadIdx.x; i < DIM / 4; i += 256) {
    float4 v = *(const float4*)&xr[i * 4];
    float4 g = *(const float4*)&wgt[i * 4];
    ushort4 hi;
    hi.x = f2bf(v.x * scale * g.x);
    hi.y = f2bf(v.y * scale * g.y);
    hi.z = f2bf(v.z * scale * g.z);
    hi.w = f2bf(v.w * scale * g.w);
    *(ushort4*)&th[(size_t)row * DIM + i * 4] = hi;
  }
}

// ---------------- fp32 -> bf16 convert, two arrays in one launch ----------------
__global__ __launch_bounds__(256) void conv2(
    const float* __restrict__ s1, u16* __restrict__ d1, long n1,
    const float* __restrict__ s2, u16* __restrict__ d2, long n2) {
  long idx = (long)blockIdx.x * 256 + threadIdx.x;
  const float* src; u16* dst; long i;
  if (idx < n1) { src = s1; dst = d1; i = idx; }
  else if (idx < n1 + n2) { src = s2; dst = d2; i = idx - n1; }
  else return;
  float4 v = *(const float4*)&src[i * 4];
  ushort4 h;
  h.x = f2bf(v.x); h.y = f2bf(v.y); h.z = f2bf(v.z); h.w = f2bf(v.w);
  *(ushort4*)&dst[i * 4] = h;
}

// ================= 128x128 tile GEMM, SPLIT-K (v7) =================
// Six rounds of evidence: every schedule variant of this structure lands on
// m102's residency curve (1/CU->320 TF, 4/CU->833 TF). M=1536 gives grids of
// 276-480 blocks -> 1-2 blocks/CU -> ~500 TF. Split-K multiplies the grid:
// rope z=2 (960 blocks, 3.75/CU), bt z=4 (1104 blocks, 4.3/CU). The K-loop is
// the R4-verified m97 structure unchanged (depth-3, counted vmcnt(8/4/0),
// conflict-free slot swizzle, gload_lds w16). GEMMs write f32 partials;
// epilogue kernels (qk_epi, v_epi, bt_red) do bias/RoPE/bf16/reduction.

// ---------------- QKV GEMM, split-K=2, partial f32 out ----------------
__global__ __launch_bounds__(256, 3) void gemm_rope(
    const u16* __restrict__ A, const u16* __restrict__ B,
    float* __restrict__ P) {
  __shared__ u16 As[3 * 4096];
  __shared__ u16 Bs[3 * 4096];
  const int K = DIM;
  const int t = threadIdx.x;
  const int lane = t & 63, w = t >> 6;
  const int z = blockIdx.z;
  const int kbase = z * (DIM / 2);   // 1440

  const int nby = gridDim.y;  // 12
  const int nwg = gridDim.x * nby;  // 480 per z-slice
  int orig = blockIdx.x * nby + blockIdx.y;
  {
    int q = nwg >> 3, r = nwg & 7;
    int xcd = orig & 7, i = orig >> 3;
    orig = (xcd < r ? xcd * (q + 1) : r * (q + 1) + (xcd - r) * q) + i;
  }
  const int m0 = (orig % nby) * 128, n0 = (orig / nby) * 128;

  const int wr = (w >> 1) * 64, wc = (w & 1) * 64;
  const int lr = lane & 15, lk8 = (lane >> 4) * 8;
  const int lcol = lk8 ^ (((lr >> 1) & 3) << 3);
  const int g4 = (lane >> 4) * 4;
  f32x4 acc[4][4] = {};

  const int ks = ((t & 3) ^ ((t >> 3) & 3)) * 8;
  const size_t ga0 = (size_t)(m0 + (t >> 2)) * K + ks + kbase;
  const size_t ga1 = (size_t)(m0 + 64 + (t >> 2)) * K + ks + kbase;
  const size_t gb0 = (size_t)(n0 + (t >> 2)) * K + ks + kbase;
  const size_t gb1 = (size_t)(n0 + 64 + (t >> 2)) * K + ks + kbase;

  auto STAGE = [&](int buf, int k0) {
    GLOAD16(A + ga0 + k0, &As[buf * 4096 + t * 8]);
    GLOAD16(A + ga1 + k0, &As[buf * 4096 + (t + 256) * 8]);
    GLOAD16(B + gb0 + k0, &Bs[buf * 4096 + t * 8]);
    GLOAD16(B + gb1 + k0, &Bs[buf * 4096 + (t + 256) * 8]);
  };

  const int nk = (DIM / 2) / 32;   // 45
  STAGE(0, 0); STAGE(1, 32);

  for (int tt = 0; tt < nk; ++tt) {
    const int cur = tt % 3;
    if (tt + 2 < nk) {
      STAGE((tt + 2) % 3, (tt + 2) * 32);
      asm volatile("s_waitcnt vmcnt(8)" ::: "memory");
    } else if (tt + 1 < nk) {
      asm volatile("s_waitcnt vmcnt(4)" ::: "memory");
    } else {
      asm volatile("s_waitcnt vmcnt(0)" ::: "memory");
    }
    __builtin_amdgcn_s_barrier();
    __builtin_amdgcn_sched_barrier(0);
    const u16* as_ = &As[cur * 4096];
    const u16* bs_ = &Bs[cur * 4096];
    bf16x8 af[4], bf_[4];
#pragma unroll
    for (int i = 0; i < 4; ++i) af[i] = *(const bf16x8*)&as_[(wr + i * 16 + lr) * 32 + lcol];
#pragma unroll
    for (int j = 0; j < 4; ++j) bf_[j] = *(const bf16x8*)&bs_[(wc + j * 16 + lr) * 32 + lcol];
    __builtin_amdgcn_s_setprio(1);
#pragma unroll
    for (int i = 0; i < 4; ++i)
#pragma unroll
      for (int j = 0; j < 4; ++j)
        acc[i][j] = __builtin_amdgcn_mfma_f32_16x16x32_bf16(af[i], bf_[j], acc[i][j], 0, 0, 0);
    __builtin_amdgcn_s_setprio(0);
    __builtin_amdgcn_sched_barrier(0);
    __builtin_amdgcn_s_barrier();
  }

  float* Pz = P + (size_t)z * S_LEN * QKV_N;
#pragma unroll
  for (int i = 0; i < 4; ++i) {
    const int row = m0 + wr + i * 16 + g4;
#pragma unroll
    for (int j = 0; j < 4; ++j) {
      const int col = n0 + wc + j * 16 + lr;
#pragma unroll
      for (int r = 0; r < 4; ++r)
        Pz[(size_t)(row + r) * QKV_N + col] = acc[i][j][r];
    }
  }
}

// ---------------- Q/K epilogue: sum halves + bias + RoPE + bf16 ----------------
__global__ __launch_bounds__(256) void qk_epi(
    const float* __restrict__ P, const float* __restrict__ bias,
    const float* __restrict__ cosT, const float* __restrict__ sinT,
    u16* __restrict__ Qb, u16* __restrict__ Kb) {
  const int idx = blockIdx.x * 256 + threadIdx.x;
  if (idx >= S_LEN * 2304) return;
  const int row = idx / 2304, it = idx % 2304;
  int col; float sc; bool isQ;
  if (it < 2048) { int h = it >> 5, dd = it & 31; col = h * 64 + dd; sc = SM_SCALE; isQ = true; }
  else { int it2 = it - 2048; int kh = it2 >> 5, dd = it2 & 31; col = 4096 + kh * 64 + dd; sc = 1.0f; isQ = false; }
  const int dd = col & 31;
  const float* P0 = P + (size_t)row * QKV_N;
  const float* P1 = P0 + (size_t)S_LEN * QKV_N;
  const float x1 = P0[col] + P1[col] + bias[col];
  const float x2 = P0[col + 32] + P1[col + 32] + bias[col + 32];
  const float c = cosT[row * 32 + dd];
  const float s = sinT[row * 32 + dd];
  const float o1 = (x1 * c - x2 * s) * sc;
  const float o2 = (x2 * c + x1 * s) * sc;
  if (isQ) {
    Qb[(size_t)row * QDIM + col] = f2bf(o1);
    Qb[(size_t)row * QDIM + col + 32] = f2bf(o2);
  } else {
    Kb[(size_t)row * KVDIM + (col - 4096)] = f2bf(o1);
    Kb[(size_t)row * KVDIM + (col - 4096) + 32] = f2bf(o2);
  }
}

// ---------------- V epilogue: sum halves + bias + bf16, transposed ----------------
__global__ __launch_bounds__(256) void v_epi(
    const float* __restrict__ P, const float* __restrict__ bias,
    u16* __restrict__ Vt) {
  const int vc = blockIdx.x;           // 0..511
  const int col = 4608 + vc;
  const float bb = bias[col];
  const float* P0 = P + col;
  const float* P1 = P0 + (size_t)S_LEN * QKV_N;
  for (int rr = threadIdx.x; rr < S_LEN; rr += 256) {
    const float v = P0[(size_t)rr * QKV_N] + P1[(size_t)rr * QKV_N] + bb;
    Vt[(size_t)vc * S_LEN + rr] = f2bf(v);
  }
}

// ---------------- out GEMM: split-K=4, partial f32 out ----------------
__global__ __launch_bounds__(256, 3) void gemm_bt(
    const u16* __restrict__ A, const u16* __restrict__ B,
    float* __restrict__ P, int M, int N, int K) {
  __shared__ u16 As[3 * 4096];
  __shared__ u16 Bs[3 * 4096];
  const int t = threadIdx.x;
  const int lane = t & 63, w = t >> 6;
  const int z = blockIdx.z;
  const int kbase = z * (K / 4);   // 1024

  const int nby = gridDim.y;  // 12
  const int nwg = gridDim.x * nby;  // 276 per z-slice
  int orig = blockIdx.x * nby + blockIdx.y;
  {
    int q = nwg >> 3, r = nwg & 7;
    int xcd = orig & 7, i = orig >> 3;
    orig = (xcd < r ? xcd * (q + 1) : r * (q + 1) + (xcd - r) * q) + i;
  }
  const int m0 = (orig % nby) * 128, n0 = (orig / nby) * 128;

  const int wr = (w >> 1) * 64, wc = (w & 1) * 64;
  const int lr = lane & 15, lk8 = (lane >> 4) * 8;
  const int lcol = lk8 ^ (((lr >> 1) & 3) << 3);
  const int g4 = (lane >> 4) * 4;
  f32x4 acc[4][4] = {};

  const int ks = ((t & 3) ^ ((t >> 3) & 3)) * 8;
  int rB0 = n0 + (t >> 2); if (rB0 > N - 1) rB0 = N - 1;
  int rB1 = n0 + 64 + (t >> 2); if (rB1 > N - 1) rB1 = N - 1;
  const size_t ga0 = (size_t)(m0 + (t >> 2)) * K + ks + kbase;
  const size_t ga1 = (size_t)(m0 + 64 + (t >> 2)) * K + ks + kbase;
  const size_t gb0 = (size_t)rB0 * K + ks + kbase;
  const size_t gb1 = (size_t)rB1 * K + ks + kbase;

  auto STAGE = [&](int buf, int k0) {
    GLOAD16(A + ga0 + k0, &As[buf * 4096 + t * 8]);
    GLOAD16(A + ga1 + k0, &As[buf * 4096 + (t + 256) * 8]);
    GLOAD16(B + gb0 + k0, &Bs[buf * 4096 + t * 8]);
    GLOAD16(B + gb1 + k0, &Bs[buf * 4096 + (t + 256) * 8]);
  };

  const int nk = (K / 4) / 32;   // 32
  STAGE(0, 0); STAGE(1, 32);

  for (int tt = 0; tt < nk; ++tt) {
    const int cur = tt % 3;
    if (tt + 2 < nk) {
      STAGE((tt + 2) % 3, (tt + 2) * 32);
      asm volatile("s_waitcnt vmcnt(8)" ::: "memory");
    } else if (tt + 1 < nk) {
      asm volatile("s_waitcnt vmcnt(4)" ::: "memory");
    } else {
      asm volatile("s_waitcnt vmcnt(0)" ::: "memory");
    }
    __builtin_amdgcn_s_barrier();
    __builtin_amdgcn_sched_barrier(0);
    const u16* as_ = &As[cur * 4096];
    const u16* bs_ = &Bs[cur * 4096];
    bf16x8 af[4], bf_[4];
#pragma unroll
    for (int i = 0; i < 4; ++i) af[i] = *(const bf16x8*)&as_[(wr + i * 16 + lr) * 32 + lcol];
#pragma unroll
    for (int j = 0; j < 4; ++j) bf_[j] = *(const bf16x8*)&bs_[(wc + j * 16 + lr) * 32 + lcol];
    __builtin_amdgcn_s_setprio(1);
#pragma unroll
    for (int i = 0; i < 4; ++i)
#pragma unroll
      for (int j = 0; j < 4; ++j)
        acc[i][j] = __builtin_amdgcn_mfma_f32_16x16x32_bf16(af[i], bf_[j], acc[i][j], 0, 0, 0);
    __builtin_amdgcn_s_setprio(0);
    __builtin_amdgcn_sched_barrier(0);
    __builtin_amdgcn_s_barrier();
  }

  float* Pz = P + (size_t)z * S_LEN * DIM;
#pragma unroll
  for (int i = 0; i < 4; ++i) {
    const int row = m0 + wr + i * 16 + g4;
#pragma unroll
    for (int j = 0; j < 4; ++j) {
      const int col = n0 + wc + j * 16 + lr;
      if (col < N) {
#pragma unroll
        for (int r = 0; r < 4; ++r)
          Pz[(size_t)(row + r) * N + col] = acc[i][j][r];
      }
    }
  }
}

// ---------------- bt reduction: sum 4 partials + bias -> fp32 out ----------------
__global__ __launch_bounds__(256) void bt_red(
    const float* __restrict__ P, const float* __restrict__ bias,
    float* __restrict__ out) {
  const long idx = (long)blockIdx.x * 256 + threadIdx.x;
  const long n4 = (long)S_LEN * DIM / 4;
  if (idx >= n4) return;
  const long row = idx / (DIM / 4), c4 = idx % (DIM / 4);
  const long base = row * DIM + c4 * 4;
  const size_t stride = (size_t)S_LEN * DIM;
  float4 s0 = *(const float4*)&P[base];
  float4 s1 = *(const float4*)&P[base + stride];
  float4 s2 = *(const float4*)&P[base + 2 * stride];
  float4 s3 = *(const float4*)&P[base + 3 * stride];
  float4 bb = *(const float4*)&bias[c4 * 4];
  float4 o;
  o.x = s0.x + s1.x + s2.x + s3.x + bb.x;
  o.y = s0.y + s1.y + s2.y + s3.y + bb.y;
  o.z = s0.z + s1.z + s2.z + s3.z + bb.z;
  o.w = s0.w + s1.w + s2.w + s3.w + bb.w;
  *(float4*)&out[base] = o;
}

// ---------------- LDS-free fused attention (swapped-operand MFMA) ----------------
__global__ __launch_bounds__(256) void attn2(
    const u16* __restrict__ Q, const u16* __restrict__ Kb, const u16* __restrict__ Vt,
    const float* __restrict__ sinks, u16* __restrict__ O) {
  const int h = blockIdx.x;
  const int kh = h >> 3;
  const int wid = threadIdx.x >> 6;
  const int lane = threadIdx.x & 63;
  const int q0 = blockIdx.y * 128 + wid * 32;
  const int lr = lane & 15;
  const int g = lane >> 4;

  bf16x8 bq[2][2];
#pragma unroll
  for (int qf = 0; qf < 2; ++qf)
#pragma unroll
    for (int kc = 0; kc < 2; ++kc)
      bq[qf][kc] = *(const bf16x8*)&Q[(size_t)(q0 + qf * 16 + lr) * QDIM + h * HD + kc * 32 + g * 8];

  f32x4 o[2][4] = {};
  float m_s[2] = {-1e30f, -1e30f};
  float l_s[2] = {0.f, 0.f};

  int js = q0 - 128; if (js < 0) js = 0;

  for (int j0 = js; j0 <= q0; j0 += 32) {
    bf16x8 ak[2][2];
#pragma unroll
    for (int jf = 0; jf < 2; ++jf)
#pragma unroll
      for (int kc = 0; kc < 2; ++kc)
        ak[jf][kc] = *(const bf16x8*)&Kb[(size_t)(j0 + jf * 16 + lr) * KVDIM + kh * HD + kc * 32 + g * 8];

    f32x4 st[2][2] = {};
#pragma unroll
    for (int jf = 0; jf < 2; ++jf)
#pragma unroll
      for (int qf = 0; qf < 2; ++qf) {
        st[jf][qf] = __builtin_amdgcn_mfma_f32_16x16x32_bf16(ak[jf][0], bq[qf][0], st[jf][qf], 0, 0, 0);
        st[jf][qf] = __builtin_amdgcn_mfma_f32_16x16x32_bf16(ak[jf][1], bq[qf][1], st[jf][qf], 0, 0, 0);
      }

    float pv[2][2][4];
    float tmax[2] = {-1e30f, -1e30f};
#pragma unroll
    for (int jf = 0; jf < 2; ++jf)
#pragma unroll
      for (int qf = 0; qf < 2; ++qf)
#pragma unroll
        for (int r = 0; r < 4; ++r) {
          int jv = j0 + jf * 16 + 4 * g + r;
          int qq = q0 + qf * 16 + lr;
          float sc = st[jf][qf][r];
          bool ok = (jv <= qq) && (qq - jv < WIN);
          sc = ok ? sc : -1e30f;
          pv[jf][qf][r] = sc;
          tmax[qf] = fmaxf(tmax[qf], sc);
        }
#pragma unroll
    for (int qf = 0; qf < 2; ++qf) {
      float tm = tmax[qf];
      tm = fmaxf(tm, __shfl_xor(tm, 16));
      tm = fmaxf(tm, __shfl_xor(tm, 32));
      const float mo = m_s[qf];
      const float mn = fmaxf(mo, tm);
      const float esc = __expf(mo - mn);
      float ps = 0.f;
#pragma unroll
      for (int jf = 0; jf < 2; ++jf)
#pragma unroll
        for (int r = 0; r < 4; ++r) {
          float sv = pv[jf][qf][r];
          float e = __expf(sv - mn);
          e = (sv <= -1e29f) ? 0.f : e;
          pv[jf][qf][r] = e;
          ps += e;
        }
      ps += __shfl_xor(ps, 16);
      ps += __shfl_xor(ps, 32);
      l_s[qf] = l_s[qf] * esc + ps;
      m_s[qf] = mn;
#pragma unroll
      for (int df = 0; df < 4; ++df) o[qf][df] *= esc;
    }

    bf16x8 pb[2];
    const int srcA = lr + ((g & 1) ? 32 : 0);
    const int srcB = srcA + 16;
    const bool hi_half = (g >= 2);
#pragma unroll
    for (int qf = 0; qf < 2; ++qf) {
      u32 w0a = pk2bf(pv[0][qf][0], pv[0][qf][1]);
      u32 w1a = pk2bf(pv[0][qf][2], pv[0][qf][3]);
      u32 w0b = pk2bf(pv[1][qf][0], pv[1][qf][1]);
      u32 w1b = pk2bf(pv[1][qf][2], pv[1][qf][3]);
      u32 a0 = (u32)__shfl((int)w0a, srcA, 64);
      u32 a1 = (u32)__shfl((int)w1a, srcA, 64);
      u32 a2 = (u32)__shfl((int)w0a, srcB, 64);
      u32 a3 = (u32)__shfl((int)w1a, srcB, 64);
      u32 b0 = (u32)__shfl((int)w0b, srcA, 64);
      u32 b1 = (u32)__shfl((int)w1b, srcA, 64);
      u32 b2 = (u32)__shfl((int)w0b, srcB, 64);
      u32 b3 = (u32)__shfl((int)w1b, srcB, 64);
      union { u32 d[4]; bf16x8 v; } u_;
      u_.d[0] = hi_half ? b0 : a0;
      u_.d[1] = hi_half ? b1 : a1;
      u_.d[2] = hi_half ? b2 : a2;
      u_.d[3] = hi_half ? b3 : a3;
      pb[qf] = u_.v;
    }

    bf16x8 av[4];
#pragma unroll
    for (int df = 0; df < 4; ++df)
      av[df] = *(const bf16x8*)&Vt[((size_t)kh * HD + df * 16 + lr) * S_LEN + j0 + g * 8];

#pragma unroll
    for (int qf = 0; qf < 2; ++qf)
#pragma unroll
      for (int df = 0; df < 4; ++df)
        o[qf][df] = __builtin_amdgcn_mfma_f32_16x16x32_bf16(av[df], pb[qf], o[qf][df], 0, 0, 0);
  }

  const float snk = sinks[h];
#pragma unroll
  for (int qf = 0; qf < 2; ++qf) {
    const float mo = m_s[qf];
    const float Mx = fmaxf(mo, snk);
    const float den = l_s[qf] * __expf(mo - Mx) + __expf(snk - Mx);
    const float osc = __expf(mo - Mx) / den;
    const int row = q0 + qf * 16 + lr;
#pragma unroll
    for (int df = 0; df < 4; ++df) {
      ushort4 pk;
      pk.x = f2bf(o[qf][df][0] * osc);
      pk.y = f2bf(o[qf][df][1] * osc);
      pk.z = f2bf(o[qf][df][2] * osc);
      pk.w = f2bf(o[qf][df][3] * osc);
      *(ushort4*)&O[(size_t)row * QDIM + h * HD + df * 16 + 4 * g] = pk;
    }
  }
}

// ---------------- launcher ----------------
extern "C" void kernel_launch(void* const* d_in, const int* in_sizes, int n_in,
                              void* d_out, int out_size, void* d_ws, size_t ws_size,
                              hipStream_t stream) {
  const float* x      = (const float*)d_in[0];
  const float* sinks  = (const float*)d_in[1];
  const float* norm_w = (const float*)d_in[2];
  const float* qkv_w  = (const float*)d_in[3];
  const float* qkv_b  = (const float*)d_in[4];
  const float* out_w  = (const float*)d_in[5];
  const float* out_b  = (const float*)d_in[6];
  float* out = (float*)d_out;

  char* ws = (char*)d_ws;
  size_t off = 0;
  auto take = [&](size_t bytes) -> void* {
    void* r = ws + off;
    off += (bytes + 255) & ~(size_t)255;
    return r;
  };
  float* cosT = (float*)take((size_t)S_LEN * 32 * 4);
  float* sinT = (float*)take((size_t)S_LEN * 32 * 4);
  u16* th  = (u16*)take((size_t)S_LEN * DIM * 2);
  u16* wh  = (u16*)take((size_t)QKV_N * DIM * 2);
  u16* ow  = (u16*)take((size_t)DIM * QDIM * 2);
  u16* Qb  = (u16*)take((size_t)S_LEN * QDIM * 2);
  u16* Kb  = (u16*)take((size_t)S_LEN * KVDIM * 2);
  u16* Vt  = (u16*)take((size_t)S_LEN * KVDIM * 2);
  u16* Ab  = (u16*)take((size_t)S_LEN * QDIM * 2);
  // partial buffer, aliased: rope needs 2*S*5120 f32 (62.9MB), bt needs
  // 4*S*2880 f32 (70.8MB); lifetimes disjoint.
  float* Pp = (float*)take((size_t)4 * S_LEN * DIM * 4);

  const long n1 = (long)QKV_N * DIM / 4;
  const long n2 = (long)DIM * QDIM / 4;

  rope_tables<<<(S_LEN * 32 + 255) / 256, 256, 0, stream>>>(cosT, sinT);
  rmsnorm_bf16<<<S_LEN, 256, 0, stream>>>(x, norm_w, th);
  conv2<<<(int)((n1 + n2 + 255) / 256), 256, 0, stream>>>(qkv_w, wh, n1, out_w, ow, n2);
  gemm_rope<<<dim3(QKV_N / 128, S_LEN / 128, 2), 256, 0, stream>>>(th, wh, Pp);
  qk_epi<<<(S_LEN * 2304 + 255) / 256, 256, 0, stream>>>(Pp, qkv_b, cosT, sinT, Qb, Kb);
  v_epi<<<512, 256, 0, stream>>>(Pp, qkv_b, Vt);
  attn2<<<dim3(NQH, S_LEN / 128), 256, 0, stream>>>(Qb, Kb, Vt, sinks, Ab);
  gemm_bt<<<dim3((DIM + 127) / 128, S_LEN / 128, 4), 256, 0, stream>>>(
      Ab, ow, Pp, S_LEN, DIM, QDIM);
  bt_red<<<(int)(((long)S_LEN * DIM / 4 + 255) / 256), 256, 0, stream>>>(Pp, out_b, out);
}

// Round 7
// 186.605 us; speedup vs baseline: 1.4198x; 1.2996x over previous
//
#include <hip/hip_runtime.h>

typedef unsigned short u16;
typedef unsigned int u32;
typedef __bf16 bf16x8 __attribute__((ext_vector_type(8)));
typedef float f32x4 __attribute__((ext_vector_type(4)));

#define S_LEN 1536
#define DIM 2880
#define NQH 64
#define NKVH 8
#define HD 64
#define QKV_N 5120
#define QDIM 4096
#define KVDIM 512
#define WIN 128
#define SM_SCALE 0.125f

// pre_all block partition
#define CONV_BLOCKS 25920   // (5120*2880/4 + 2880*4096/4)/256
#define RMS_BLOCKS 1536
#define ROPE_BLOCKS 192     // 1536*32/256

__device__ __forceinline__ u16 f2bf(float f) {
  union { float f; u32 u; } a; a.f = f;
  u32 u = a.u;
  u32 lsb = (u >> 16) & 1;
  u += 0x7fffu + lsb;
  return (u16)(u >> 16);
}
__device__ __forceinline__ u32 pk2bf(float a, float b) {
  return (u32)f2bf(a) | ((u32)f2bf(b) << 16);
}

#define GLOAD16(g, l) __builtin_amdgcn_global_load_lds( \
    (const __attribute__((address_space(1))) u32*)(g), \
    (__attribute__((address_space(3))) u32*)(l), 16, 0, 0)

// ---------------- merged preamble: conv2 + rmsnorm + rope tables ----------------
__global__ __launch_bounds__(256) void pre_all(
    const float* __restrict__ x, const float* __restrict__ norm_w,
    u16* __restrict__ th,
    const float* __restrict__ qkv_w, u16* __restrict__ wh,
    const float* __restrict__ out_w, u16* __restrict__ ow,
    float* __restrict__ cosT, float* __restrict__ sinT) {
  const int b = blockIdx.x;
  if (b < CONV_BLOCKS) {
    // fp32 -> bf16 convert of both weight matrices
    const long n1 = (long)QKV_N * DIM / 4;
    const long n2 = (long)DIM * QDIM / 4;
    long idx = (long)b * 256 + threadIdx.x;
    const float* src; u16* dst; long i;
    if (idx < n1) { src = qkv_w; dst = wh; i = idx; }
    else if (idx < n1 + n2) { src = out_w; dst = ow; i = idx - n1; }
    else return;
    float4 v = *(const float4*)&src[i * 4];
    ushort4 h;
    h.x = f2bf(v.x); h.y = f2bf(v.y); h.z = f2bf(v.z); h.w = f2bf(v.w);
    *(ushort4*)&dst[i * 4] = h;
  } else if (b < CONV_BLOCKS + RMS_BLOCKS) {
    // RMSNorm row
    const int row = b - CONV_BLOCKS;
    const float* xr = x + (size_t)row * DIM;
    float ss = 0.f;
    for (int i = threadIdx.x; i < DIM / 4; i += 256) {
      float4 v = *(const float4*)&xr[i * 4];
      ss += v.x * v.x + v.y * v.y + v.z * v.z + v.w * v.w;
    }
    for (int m = 32; m >= 1; m >>= 1) ss += __shfl_xor(ss, m);
    __shared__ float red[4];
    int lane = threadIdx.x & 63, w = threadIdx.x >> 6;
    if (lane == 0) red[w] = ss;
    __syncthreads();
    float tot = red[0] + red[1] + red[2] + red[3];
    float scale = rsqrtf(tot / (float)DIM + 1e-5f);
    for (int i = threadIdx.x; i < DIM / 4; i += 256) {
      float4 v = *(const float4*)&xr[i * 4];
      float4 g = *(const float4*)&norm_w[i * 4];
      ushort4 hi;
      hi.x = f2bf(v.x * scale * g.x);
      hi.y = f2bf(v.y * scale * g.y);
      hi.z = f2bf(v.z * scale * g.z);
      hi.w = f2bf(v.w * scale * g.w);
      *(ushort4*)&th[(size_t)row * DIM + i * 4] = hi;
    }
  } else {
    // YaRN rope tables
    int idx = (b - CONV_BLOCKS - RMS_BLOCKS) * 256 + threadIdx.x;
    if (idx >= S_LEN * 32) return;
    int s = idx >> 5, d = idx & 31;
    const double TWO_PI = 6.283185307179586;
    double freq = pow(150000.0, (double)d / 32.0);
    double conc = 0.1 * log(32.0) + 1.0;
    double lb = log(150000.0);
    double low = 32.0 * log(4096.0 / (32.0 * TWO_PI)) / lb;
    double high = 32.0 * log(4096.0 / (1.0 * TWO_PI)) / lb;
    double interp = 1.0 / (32.0 * freq), extra = 1.0 / freq;
    double ramp = ((double)d - low) / (high - low);
    ramp = ramp < 0.0 ? 0.0 : (ramp > 1.0 ? 1.0 : ramp);
    double maskv = 1.0 - ramp;
    double invf = interp * (1.0 - maskv) + extra * maskv;
    double ang = (double)s * invf;
    cosT[idx] = (float)(cos(ang) * conc);
    sinT[idx] = (float)(sin(ang) * conc);
  }
}

// ================= gemm_rope: 128x128 tile (R4-verified config) =================
// 256 thr = 4 waves (2x2), wave tile 64x64 (acc 4x4), BK=32, depth-3 pipeline,
// counted vmcnt(8/4/0), conflict-free slot swizzle, setprio around MFMA.
// LDS 48KB -> 3 blocks/CU; grid 40x12 = 480 blocks (1.875/CU).
__global__ __launch_bounds__(256, 3) void gemm_rope(
    const u16* __restrict__ A, const u16* __restrict__ B,
    const float* __restrict__ bias,
    const float* __restrict__ cosT, const float* __restrict__ sinT,
    u16* __restrict__ Qb, u16* __restrict__ Kb, u16* __restrict__ Vt) {
  __shared__ u16 As[3 * 4096];
  __shared__ u16 Bs[3 * 4096];
  const int K = DIM;
  const int t = threadIdx.x;
  const int lane = t & 63, w = t >> 6;

  const int nby = gridDim.y;  // 12
  const int nwg = gridDim.x * nby;
  int orig = blockIdx.x * nby + blockIdx.y;
  {
    int q = nwg >> 3, r = nwg & 7;
    int xcd = orig & 7, i = orig >> 3;
    orig = (xcd < r ? xcd * (q + 1) : r * (q + 1) + (xcd - r) * q) + i;
  }
  const int m0 = (orig % nby) * 128, n0 = (orig / nby) * 128;

  const int wr = (w >> 1) * 64, wc = (w & 1) * 64;
  const int lr = lane & 15, lk8 = (lane >> 4) * 8;
  const int lcol = lk8 ^ (((lr >> 1) & 3) << 3);
  const int g4 = (lane >> 4) * 4;
  f32x4 acc[4][4] = {};

  const int ks = ((t & 3) ^ ((t >> 3) & 3)) * 8;
  const size_t ga0 = (size_t)(m0 + (t >> 2)) * K + ks;
  const size_t ga1 = (size_t)(m0 + 64 + (t >> 2)) * K + ks;
  const size_t gb0 = (size_t)(n0 + (t >> 2)) * K + ks;
  const size_t gb1 = (size_t)(n0 + 64 + (t >> 2)) * K + ks;

  auto STAGE = [&](int buf, int k0) {
    GLOAD16(A + ga0 + k0, &As[buf * 4096 + t * 8]);
    GLOAD16(A + ga1 + k0, &As[buf * 4096 + (t + 256) * 8]);
    GLOAD16(B + gb0 + k0, &Bs[buf * 4096 + t * 8]);
    GLOAD16(B + gb1 + k0, &Bs[buf * 4096 + (t + 256) * 8]);
  };

  const int nk = K / 32;
  STAGE(0, 0); STAGE(1, 32);

  for (int tt = 0; tt < nk; ++tt) {
    const int cur = tt % 3;
    if (tt + 2 < nk) {
      STAGE((tt + 2) % 3, (tt + 2) * 32);
      asm volatile("s_waitcnt vmcnt(8)" ::: "memory");
    } else if (tt + 1 < nk) {
      asm volatile("s_waitcnt vmcnt(4)" ::: "memory");
    } else {
      asm volatile("s_waitcnt vmcnt(0)" ::: "memory");
    }
    __builtin_amdgcn_s_barrier();
    __builtin_amdgcn_sched_barrier(0);
    const u16* as_ = &As[cur * 4096];
    const u16* bs_ = &Bs[cur * 4096];
    bf16x8 af[4], bf_[4];
#pragma unroll
    for (int i = 0; i < 4; ++i) af[i] = *(const bf16x8*)&as_[(wr + i * 16 + lr) * 32 + lcol];
#pragma unroll
    for (int j = 0; j < 4; ++j) bf_[j] = *(const bf16x8*)&bs_[(wc + j * 16 + lr) * 32 + lcol];
    __builtin_amdgcn_s_setprio(1);
#pragma unroll
    for (int i = 0; i < 4; ++i)
#pragma unroll
      for (int j = 0; j < 4; ++j)
        acc[i][j] = __builtin_amdgcn_mfma_f32_16x16x32_bf16(af[i], bf_[j], acc[i][j], 0, 0, 0);
    __builtin_amdgcn_s_setprio(0);
    __builtin_amdgcn_sched_barrier(0);
    __builtin_amdgcn_s_barrier();
  }

  if (n0 < 4608) {  // q or k region: bias + rope + bf16
    const bool isQ = (n0 < 4096);
    const float sc = isQ ? SM_SCALE : 1.0f;
#pragma unroll
    for (int i = 0; i < 4; ++i) {
      const int row = m0 + wr + i * 16 + g4;
#pragma unroll
      for (int j = 0; j < 2; ++j) {
        const int col = n0 + wc + j * 16 + lr;
        const int d = j * 16 + lr;
        const float b1 = bias[col], b2 = bias[col + 32];
#pragma unroll
        for (int r = 0; r < 4; ++r) {
          const float c = cosT[(row + r) * 32 + d];
          const float s = sinT[(row + r) * 32 + d];
          const float x1 = acc[i][j][r] + b1;
          const float x2 = acc[i][j + 2][r] + b2;
          const float o1 = (x1 * c - x2 * s) * sc;
          const float o2 = (x2 * c + x1 * s) * sc;
          if (isQ) {
            Qb[(size_t)(row + r) * QDIM + col] = f2bf(o1);
            Qb[(size_t)(row + r) * QDIM + col + 32] = f2bf(o2);
          } else {
            Kb[(size_t)(row + r) * KVDIM + (col - 4096)] = f2bf(o1);
            Kb[(size_t)(row + r) * KVDIM + (col - 4096) + 32] = f2bf(o2);
          }
        }
      }
    }
  } else {  // v region: bias + bf16, transposed store Vt[vcol][s]
#pragma unroll
    for (int i = 0; i < 4; ++i) {
      const int rowb = m0 + wr + i * 16 + g4;
#pragma unroll
      for (int j = 0; j < 4; ++j) {
        const int col = n0 + wc + j * 16 + lr;
        const float bb = bias[col];
        ushort4 pk;
        pk.x = f2bf(acc[i][j][0] + bb);
        pk.y = f2bf(acc[i][j][1] + bb);
        pk.z = f2bf(acc[i][j][2] + bb);
        pk.w = f2bf(acc[i][j][3] + bb);
        *(ushort4*)&Vt[(size_t)(col - 4608) * S_LEN + rowb] = pk;
      }
    }
  }
}

// ================= gemm_bt: 64x128 tile, BK=64 dbuf (R2-verified config) =================
// 256 thr = 4 waves, wave tile 32x64 (acc 2x4), BK=64 (2 k32 subtiles),
// double-buffered depth-1, counted vmcnt(6/0). LDS 48KB -> 3 blocks/CU.
// Grid 23x24 = 552 blocks (2.16/CU) — best measured config for this GEMM.
__global__ __launch_bounds__(256, 3) void gemm_bt(
    const u16* __restrict__ A, const u16* __restrict__ B,
    const float* __restrict__ bias, float* __restrict__ C,
    int M, int N, int K) {
  __shared__ u16 As[2 * 4096];
  __shared__ u16 Bs[2 * 8192];
  const int t = threadIdx.x;
  const int lane = t & 63, w = t >> 6;

  const int nby = gridDim.y;
  const int nwg = gridDim.x * nby;
  int orig = blockIdx.x * nby + blockIdx.y;
  {
    int q = nwg >> 3, r = nwg & 7;
    int xcd = orig & 7, i = orig >> 3;
    orig = (xcd < r ? xcd * (q + 1) : r * (q + 1) + (xcd - r) * q) + i;
  }
  const int m0 = (orig % nby) * 64, n0 = (orig / nby) * 128;

  const int wr = (w >> 1) * 32, wc = (w & 1) * 64;
  const int lr = lane & 15, lk8 = (lane >> 4) * 8;
  const int lcol = lk8 ^ (((lr >> 1) & 3) << 3);
  const int g4 = (lane >> 4) * 4;
  f32x4 acc[2][4] = {};

  int rB0 = n0 + (t >> 2); if (rB0 > N - 1) rB0 = N - 1;
  int rB1 = n0 + 64 + (t >> 2); if (rB1 > N - 1) rB1 = N - 1;
  const size_t ga  = (size_t)(m0 + (t >> 2)) * K + (((t & 3) ^ ((t >> 3) & 3)) * 8);
  const size_t gb0 = (size_t)rB0 * K + (((t & 3) ^ ((t >> 3) & 3)) * 8);
  const size_t gb1 = (size_t)rB1 * K + (((t & 3) ^ ((t >> 3) & 3)) * 8);

  auto STAGE = [&](int buf, int k0) {
    GLOAD16(A + ga + k0,        &As[buf * 4096 + t * 8]);
    GLOAD16(A + ga + k0 + 32,   &As[buf * 4096 + 2048 + t * 8]);
    GLOAD16(B + gb0 + k0,       &Bs[buf * 8192 + t * 8]);
    GLOAD16(B + gb1 + k0,       &Bs[buf * 8192 + (t + 256) * 8]);
    GLOAD16(B + gb0 + k0 + 32,  &Bs[buf * 8192 + 4096 + t * 8]);
    GLOAD16(B + gb1 + k0 + 32,  &Bs[buf * 8192 + 4096 + (t + 256) * 8]);
  };

  const int nk2 = K / 64;
  STAGE(0, 0);

  for (int tt = 0; tt < nk2; ++tt) {
    const int cur = tt & 1;
    if (tt + 1 < nk2) {
      STAGE(cur ^ 1, (tt + 1) * 64);
      asm volatile("s_waitcnt vmcnt(6)" ::: "memory");
    } else {
      asm volatile("s_waitcnt vmcnt(0)" ::: "memory");
    }
    __builtin_amdgcn_s_barrier();
    __builtin_amdgcn_sched_barrier(0);
    const u16* as_ = &As[cur * 4096];
    const u16* bs_ = &Bs[cur * 8192];
    bf16x8 af[2][2], bf_[2][4];
#pragma unroll
    for (int ks = 0; ks < 2; ++ks) {
#pragma unroll
      for (int i = 0; i < 2; ++i)
        af[ks][i] = *(const bf16x8*)&as_[ks * 2048 + (wr + i * 16 + lr) * 32 + lcol];
#pragma unroll
      for (int j = 0; j < 4; ++j)
        bf_[ks][j] = *(const bf16x8*)&bs_[ks * 4096 + (wc + j * 16 + lr) * 32 + lcol];
    }
#pragma unroll
    for (int ks = 0; ks < 2; ++ks)
#pragma unroll
      for (int i = 0; i < 2; ++i)
#pragma unroll
        for (int j = 0; j < 4; ++j)
          acc[i][j] = __builtin_amdgcn_mfma_f32_16x16x32_bf16(af[ks][i], bf_[ks][j], acc[i][j], 0, 0, 0);
    __builtin_amdgcn_sched_barrier(0);
    __builtin_amdgcn_s_barrier();
  }

#pragma unroll
  for (int i = 0; i < 2; ++i) {
    const int row = m0 + wr + i * 16 + g4;
#pragma unroll
    for (int j = 0; j < 4; ++j) {
      const int col = n0 + wc + j * 16 + lr;
      if (col < N) {
        const float bb = bias[col];
#pragma unroll
        for (int r = 0; r < 4; ++r)
          C[(size_t)(row + r) * N + col] = acc[i][j][r] + bb;
      }
    }
  }
}

// ---------------- LDS-free fused attention (swapped-operand MFMA) ----------------
__global__ __launch_bounds__(256) void attn2(
    const u16* __restrict__ Q, const u16* __restrict__ Kb, const u16* __restrict__ Vt,
    const float* __restrict__ sinks, u16* __restrict__ O) {
  const int h = blockIdx.x;
  const int kh = h >> 3;
  const int wid = threadIdx.x >> 6;
  const int lane = threadIdx.x & 63;
  const int q0 = blockIdx.y * 128 + wid * 32;
  const int lr = lane & 15;
  const int g = lane >> 4;

  bf16x8 bq[2][2];
#pragma unroll
  for (int qf = 0; qf < 2; ++qf)
#pragma unroll
    for (int kc = 0; kc < 2; ++kc)
      bq[qf][kc] = *(const bf16x8*)&Q[(size_t)(q0 + qf * 16 + lr) * QDIM + h * HD + kc * 32 + g * 8];

  f32x4 o[2][4] = {};
  float m_s[2] = {-1e30f, -1e30f};
  float l_s[2] = {0.f, 0.f};

  int js = q0 - 128; if (js < 0) js = 0;

  for (int j0 = js; j0 <= q0; j0 += 32) {
    bf16x8 ak[2][2];
#pragma unroll
    for (int jf = 0; jf < 2; ++jf)
#pragma unroll
      for (int kc = 0; kc < 2; ++kc)
        ak[jf][kc] = *(const bf16x8*)&Kb[(size_t)(j0 + jf * 16 + lr) * KVDIM + kh * HD + kc * 32 + g * 8];

    f32x4 st[2][2] = {};
#pragma unroll
    for (int jf = 0; jf < 2; ++jf)
#pragma unroll
      for (int qf = 0; qf < 2; ++qf) {
        st[jf][qf] = __builtin_amdgcn_mfma_f32_16x16x32_bf16(ak[jf][0], bq[qf][0], st[jf][qf], 0, 0, 0);
        st[jf][qf] = __builtin_amdgcn_mfma_f32_16x16x32_bf16(ak[jf][1], bq[qf][1], st[jf][qf], 0, 0, 0);
      }

    float pv[2][2][4];
    float tmax[2] = {-1e30f, -1e30f};
#pragma unroll
    for (int jf = 0; jf < 2; ++jf)
#pragma unroll
      for (int qf = 0; qf < 2; ++qf)
#pragma unroll
        for (int r = 0; r < 4; ++r) {
          int jv = j0 + jf * 16 + 4 * g + r;
          int qq = q0 + qf * 16 + lr;
          float sc = st[jf][qf][r];
          bool ok = (jv <= qq) && (qq - jv < WIN);
          sc = ok ? sc : -1e30f;
          pv[jf][qf][r] = sc;
          tmax[qf] = fmaxf(tmax[qf], sc);
        }
#pragma unroll
    for (int qf = 0; qf < 2; ++qf) {
      float tm = tmax[qf];
      tm = fmaxf(tm, __shfl_xor(tm, 16));
      tm = fmaxf(tm, __shfl_xor(tm, 32));
      const float mo = m_s[qf];
      const float mn = fmaxf(mo, tm);
      const float esc = __expf(mo - mn);
      float ps = 0.f;
#pragma unroll
      for (int jf = 0; jf < 2; ++jf)
#pragma unroll
        for (int r = 0; r < 4; ++r) {
          float sv = pv[jf][qf][r];
          float e = __expf(sv - mn);
          e = (sv <= -1e29f) ? 0.f : e;
          pv[jf][qf][r] = e;
          ps += e;
        }
      ps += __shfl_xor(ps, 16);
      ps += __shfl_xor(ps, 32);
      l_s[qf] = l_s[qf] * esc + ps;
      m_s[qf] = mn;
#pragma unroll
      for (int df = 0; df < 4; ++df) o[qf][df] *= esc;
    }

    bf16x8 pb[2];
    const int srcA = lr + ((g & 1) ? 32 : 0);
    const int srcB = srcA + 16;
    const bool hi_half = (g >= 2);
#pragma unroll
    for (int qf = 0; qf < 2; ++qf) {
      u32 w0a = pk2bf(pv[0][qf][0], pv[0][qf][1]);
      u32 w1a = pk2bf(pv[0][qf][2], pv[0][qf][3]);
      u32 w0b = pk2bf(pv[1][qf][0], pv[1][qf][1]);
      u32 w1b = pk2bf(pv[1][qf][2], pv[1][qf][3]);
      u32 a0 = (u32)__shfl((int)w0a, srcA, 64);
      u32 a1 = (u32)__shfl((int)w1a, srcA, 64);
      u32 a2 = (u32)__shfl((int)w0a, srcB, 64);
      u32 a3 = (u32)__shfl((int)w1a, srcB, 64);
      u32 b0 = (u32)__shfl((int)w0b, srcA, 64);
      u32 b1 = (u32)__shfl((int)w1b, srcA, 64);
      u32 b2 = (u32)__shfl((int)w0b, srcB, 64);
      u32 b3 = (u32)__shfl((int)w1b, srcB, 64);
      union { u32 d[4]; bf16x8 v; } u_;
      u_.d[0] = hi_half ? b0 : a0;
      u_.d[1] = hi_half ? b1 : a1;
      u_.d[2] = hi_half ? b2 : a2;
      u_.d[3] = hi_half ? b3 : a3;
      pb[qf] = u_.v;
    }

    bf16x8 av[4];
#pragma unroll
    for (int df = 0; df < 4; ++df)
      av[df] = *(const bf16x8*)&Vt[((size_t)kh * HD + df * 16 + lr) * S_LEN + j0 + g * 8];

#pragma unroll
    for (int qf = 0; qf < 2; ++qf)
#pragma unroll
      for (int df = 0; df < 4; ++df)
        o[qf][df] = __builtin_amdgcn_mfma_f32_16x16x32_bf16(av[df], pb[qf], o[qf][df], 0, 0, 0);
  }

  const float snk = sinks[h];
#pragma unroll
  for (int qf = 0; qf < 2; ++qf) {
    const float mo = m_s[qf];
    const float Mx = fmaxf(mo, snk);
    const float den = l_s[qf] * __expf(mo - Mx) + __expf(snk - Mx);
    const float osc = __expf(mo - Mx) / den;
    const int row = q0 + qf * 16 + lr;
#pragma unroll
    for (int df = 0; df < 4; ++df) {
      ushort4 pk;
      pk.x = f2bf(o[qf][df][0] * osc);
      pk.y = f2bf(o[qf][df][1] * osc);
      pk.z = f2bf(o[qf][df][2] * osc);
      pk.w = f2bf(o[qf][df][3] * osc);
      *(ushort4*)&O[(size_t)row * QDIM + h * HD + df * 16 + 4 * g] = pk;
    }
  }
}

// ---------------- launcher ----------------
extern "C" void kernel_launch(void* const* d_in, const int* in_sizes, int n_in,
                              void* d_out, int out_size, void* d_ws, size_t ws_size,
                              hipStream_t stream) {
  const float* x      = (const float*)d_in[0];
  const float* sinks  = (const float*)d_in[1];
  const float* norm_w = (const float*)d_in[2];
  const float* qkv_w  = (const float*)d_in[3];
  const float* qkv_b  = (const float*)d_in[4];
  const float* out_w  = (const float*)d_in[5];
  const float* out_b  = (const float*)d_in[6];
  float* out = (float*)d_out;

  char* ws = (char*)d_ws;
  size_t off = 0;
  auto take = [&](size_t bytes) -> void* {
    void* r = ws + off;
    off += (bytes + 255) & ~(size_t)255;
    return r;
  };
  float* cosT = (float*)take((size_t)S_LEN * 32 * 4);
  float* sinT = (float*)take((size_t)S_LEN * 32 * 4);
  u16* th  = (u16*)take((size_t)S_LEN * DIM * 2);
  u16* wh  = (u16*)take((size_t)QKV_N * DIM * 2);
  u16* ow  = (u16*)take((size_t)DIM * QDIM * 2);
  u16* Qb  = (u16*)take((size_t)S_LEN * QDIM * 2);
  u16* Kb  = (u16*)take((size_t)S_LEN * KVDIM * 2);
  u16* Vt  = (u16*)take((size_t)S_LEN * KVDIM * 2);
  u16* Ab  = (u16*)take((size_t)S_LEN * QDIM * 2);

  pre_all<<<CONV_BLOCKS + RMS_BLOCKS + ROPE_BLOCKS, 256, 0, stream>>>(
      x, norm_w, th, qkv_w, wh, out_w, ow, cosT, sinT);
  gemm_rope<<<dim3(QKV_N / 128, S_LEN / 128), 256, 0, stream>>>(
      th, wh, qkv_b, cosT, sinT, Qb, Kb, Vt);
  attn2<<<dim3(NQH, S_LEN / 128), 256, 0, stream>>>(Qb, Kb, Vt, sinks, Ab);
  gemm_bt<<<dim3((DIM + 127) / 128, S_LEN / 64), 256, 0, stream>>>(
      Ab, ow, out_b, out, S_LEN, DIM, QDIM);
}

// Round 8
// 186.269 us; speedup vs baseline: 1.4224x; 1.0018x over previous
//
#include <hip/hip_runtime.h>

typedef unsigned short u16;
typedef unsigned int u32;
typedef __bf16 bf16x8 __attribute__((ext_vector_type(8)));
typedef float f32x4 __attribute__((ext_vector_type(4)));

#define S_LEN 1536
#define DIM 2880
#define NQH 64
#define NKVH 8
#define HD 64
#define QKV_N 5120
#define QDIM 4096
#define KVDIM 512
#define WIN 128
#define SM_SCALE 0.125f

// pre_all block partition (qkv_w conv + rmsnorm + rope tables)
#define CONV1_BLOCKS 14400  // 5120*2880/4/256
#define RMS_BLOCKS 1536
#define ROPE_BLOCKS 192     // 1536*32/256

// attn2 block partition: attn first (dispatched first), ow-conv tail
#define ATTN_BLOCKS 768     // 64 heads x 12 q-tiles
#define OWCONV_BLOCKS 11520 // 2880*4096/4/256

__device__ __forceinline__ u16 f2bf(float f) {
  union { float f; u32 u; } a; a.f = f;
  u32 u = a.u;
  u32 lsb = (u >> 16) & 1;
  u += 0x7fffu + lsb;
  return (u16)(u >> 16);
}
__device__ __forceinline__ u32 pk2bf(float a, float b) {
  return (u32)f2bf(a) | ((u32)f2bf(b) << 16);
}

#define GLOAD16(g, l) __builtin_amdgcn_global_load_lds( \
    (const __attribute__((address_space(1))) u32*)(g), \
    (__attribute__((address_space(3))) u32*)(l), 16, 0, 0)

// ---------------- merged preamble: qkv_w conv + rmsnorm + rope tables ----------------
__global__ __launch_bounds__(256) void pre_all(
    const float* __restrict__ x, const float* __restrict__ norm_w,
    u16* __restrict__ th,
    const float* __restrict__ qkv_w, u16* __restrict__ wh,
    float* __restrict__ cosT, float* __restrict__ sinT) {
  const int b = blockIdx.x;
  if (b < CONV1_BLOCKS) {
    long idx = (long)b * 256 + threadIdx.x;   // < 5120*2880/4 exactly
    float4 v = *(const float4*)&qkv_w[idx * 4];
    ushort4 h;
    h.x = f2bf(v.x); h.y = f2bf(v.y); h.z = f2bf(v.z); h.w = f2bf(v.w);
    *(ushort4*)&wh[idx * 4] = h;
  } else if (b < CONV1_BLOCKS + RMS_BLOCKS) {
    // RMSNorm row
    const int row = b - CONV1_BLOCKS;
    const float* xr = x + (size_t)row * DIM;
    float ss = 0.f;
    for (int i = threadIdx.x; i < DIM / 4; i += 256) {
      float4 v = *(const float4*)&xr[i * 4];
      ss += v.x * v.x + v.y * v.y + v.z * v.z + v.w * v.w;
    }
    for (int m = 32; m >= 1; m >>= 1) ss += __shfl_xor(ss, m);
    __shared__ float red[4];
    int lane = threadIdx.x & 63, w = threadIdx.x >> 6;
    if (lane == 0) red[w] = ss;
    __syncthreads();
    float tot = red[0] + red[1] + red[2] + red[3];
    float scale = rsqrtf(tot / (float)DIM + 1e-5f);
    for (int i = threadIdx.x; i < DIM / 4; i += 256) {
      float4 v = *(const float4*)&xr[i * 4];
      float4 g = *(const float4*)&norm_w[i * 4];
      ushort4 hi;
      hi.x = f2bf(v.x * scale * g.x);
      hi.y = f2bf(v.y * scale * g.y);
      hi.z = f2bf(v.z * scale * g.z);
      hi.w = f2bf(v.w * scale * g.w);
      *(ushort4*)&th[(size_t)row * DIM + i * 4] = hi;
    }
  } else {
    // YaRN rope tables
    int idx = (b - CONV1_BLOCKS - RMS_BLOCKS) * 256 + threadIdx.x;
    if (idx >= S_LEN * 32) return;
    int s = idx >> 5, d = idx & 31;
    const double TWO_PI = 6.283185307179586;
    double freq = pow(150000.0, (double)d / 32.0);
    double conc = 0.1 * log(32.0) + 1.0;
    double lb = log(150000.0);
    double low = 32.0 * log(4096.0 / (32.0 * TWO_PI)) / lb;
    double high = 32.0 * log(4096.0 / (1.0 * TWO_PI)) / lb;
    double interp = 1.0 / (32.0 * freq), extra = 1.0 / freq;
    double ramp = ((double)d - low) / (high - low);
    ramp = ramp < 0.0 ? 0.0 : (ramp > 1.0 ? 1.0 : ramp);
    double maskv = 1.0 - ramp;
    double invf = interp * (1.0 - maskv) + extra * maskv;
    double ang = (double)s * invf;
    cosT[idx] = (float)(cos(ang) * conc);
    sinT[idx] = (float)(sin(ang) * conc);
  }
}

// ================= gemm_rope: 128x128 tile (R4/R7-verified config) =================
// 256 thr = 4 waves (2x2), wave tile 64x64 (acc 4x4), BK=32, depth-3 pipeline,
// counted vmcnt(8/4/0), conflict-free slot swizzle, setprio around MFMA.
// LDS 48KB -> 3 blocks/CU; grid 40x12 = 480 blocks (all resident).
__global__ __launch_bounds__(256, 3) void gemm_rope(
    const u16* __restrict__ A, const u16* __restrict__ B,
    const float* __restrict__ bias,
    const float* __restrict__ cosT, const float* __restrict__ sinT,
    u16* __restrict__ Qb, u16* __restrict__ Kb, u16* __restrict__ Vt) {
  __shared__ u16 As[3 * 4096];
  __shared__ u16 Bs[3 * 4096];
  const int K = DIM;
  const int t = threadIdx.x;
  const int lane = t & 63, w = t >> 6;

  const int nby = gridDim.y;  // 12
  const int nwg = gridDim.x * nby;
  int orig = blockIdx.x * nby + blockIdx.y;
  {
    int q = nwg >> 3, r = nwg & 7;
    int xcd = orig & 7, i = orig >> 3;
    orig = (xcd < r ? xcd * (q + 1) : r * (q + 1) + (xcd - r) * q) + i;
  }
  const int m0 = (orig % nby) * 128, n0 = (orig / nby) * 128;

  const int wr = (w >> 1) * 64, wc = (w & 1) * 64;
  const int lr = lane & 15, lk8 = (lane >> 4) * 8;
  const int lcol = lk8 ^ (((lr >> 1) & 3) << 3);
  const int g4 = (lane >> 4) * 4;
  f32x4 acc[4][4] = {};

  const int ks = ((t & 3) ^ ((t >> 3) & 3)) * 8;
  const size_t ga0 = (size_t)(m0 + (t >> 2)) * K + ks;
  const size_t ga1 = (size_t)(m0 + 64 + (t >> 2)) * K + ks;
  const size_t gb0 = (size_t)(n0 + (t >> 2)) * K + ks;
  const size_t gb1 = (size_t)(n0 + 64 + (t >> 2)) * K + ks;

  auto STAGE = [&](int buf, int k0) {
    GLOAD16(A + ga0 + k0, &As[buf * 4096 + t * 8]);
    GLOAD16(A + ga1 + k0, &As[buf * 4096 + (t + 256) * 8]);
    GLOAD16(B + gb0 + k0, &Bs[buf * 4096 + t * 8]);
    GLOAD16(B + gb1 + k0, &Bs[buf * 4096 + (t + 256) * 8]);
  };

  const int nk = K / 32;
  STAGE(0, 0); STAGE(1, 32);

  for (int tt = 0; tt < nk; ++tt) {
    const int cur = tt % 3;
    if (tt + 2 < nk) {
      STAGE((tt + 2) % 3, (tt + 2) * 32);
      asm volatile("s_waitcnt vmcnt(8)" ::: "memory");
    } else if (tt + 1 < nk) {
      asm volatile("s_waitcnt vmcnt(4)" ::: "memory");
    } else {
      asm volatile("s_waitcnt vmcnt(0)" ::: "memory");
    }
    __builtin_amdgcn_s_barrier();
    __builtin_amdgcn_sched_barrier(0);
    const u16* as_ = &As[cur * 4096];
    const u16* bs_ = &Bs[cur * 4096];
    bf16x8 af[4], bf_[4];
#pragma unroll
    for (int i = 0; i < 4; ++i) af[i] = *(const bf16x8*)&as_[(wr + i * 16 + lr) * 32 + lcol];
#pragma unroll
    for (int j = 0; j < 4; ++j) bf_[j] = *(const bf16x8*)&bs_[(wc + j * 16 + lr) * 32 + lcol];
    __builtin_amdgcn_s_setprio(1);
#pragma unroll
    for (int i = 0; i < 4; ++i)
#pragma unroll
      for (int j = 0; j < 4; ++j)
        acc[i][j] = __builtin_amdgcn_mfma_f32_16x16x32_bf16(af[i], bf_[j], acc[i][j], 0, 0, 0);
    __builtin_amdgcn_s_setprio(0);
    __builtin_amdgcn_sched_barrier(0);
    __builtin_amdgcn_s_barrier();
  }

  if (n0 < 4608) {  // q or k region: bias + rope + bf16
    const bool isQ = (n0 < 4096);
    const float sc = isQ ? SM_SCALE : 1.0f;
#pragma unroll
    for (int i = 0; i < 4; ++i) {
      const int row = m0 + wr + i * 16 + g4;
#pragma unroll
      for (int j = 0; j < 2; ++j) {
        const int col = n0 + wc + j * 16 + lr;
        const int d = j * 16 + lr;
        const float b1 = bias[col], b2 = bias[col + 32];
#pragma unroll
        for (int r = 0; r < 4; ++r) {
          const float c = cosT[(row + r) * 32 + d];
          const float s = sinT[(row + r) * 32 + d];
          const float x1 = acc[i][j][r] + b1;
          const float x2 = acc[i][j + 2][r] + b2;
          const float o1 = (x1 * c - x2 * s) * sc;
          const float o2 = (x2 * c + x1 * s) * sc;
          if (isQ) {
            Qb[(size_t)(row + r) * QDIM + col] = f2bf(o1);
            Qb[(size_t)(row + r) * QDIM + col + 32] = f2bf(o2);
          } else {
            Kb[(size_t)(row + r) * KVDIM + (col - 4096)] = f2bf(o1);
            Kb[(size_t)(row + r) * KVDIM + (col - 4096) + 32] = f2bf(o2);
          }
        }
      }
    }
  } else {  // v region: bias + bf16, transposed store Vt[vcol][s]
#pragma unroll
    for (int i = 0; i < 4; ++i) {
      const int rowb = m0 + wr + i * 16 + g4;
#pragma unroll
      for (int j = 0; j < 4; ++j) {
        const int col = n0 + wc + j * 16 + lr;
        const float bb = bias[col];
        ushort4 pk;
        pk.x = f2bf(acc[i][j][0] + bb);
        pk.y = f2bf(acc[i][j][1] + bb);
        pk.z = f2bf(acc[i][j][2] + bb);
        pk.w = f2bf(acc[i][j][3] + bb);
        *(ushort4*)&Vt[(size_t)(col - 4608) * S_LEN + rowb] = pk;
      }
    }
  }
}

// ================= gemm_bt: 64x128 tile, BK=64 dbuf (R2/R7-verified config) =================
__global__ __launch_bounds__(256, 3) void gemm_bt(
    const u16* __restrict__ A, const u16* __restrict__ B,
    const float* __restrict__ bias, float* __restrict__ C,
    int M, int N, int K) {
  __shared__ u16 As[2 * 4096];
  __shared__ u16 Bs[2 * 8192];
  const int t = threadIdx.x;
  const int lane = t & 63, w = t >> 6;

  const int nby = gridDim.y;
  const int nwg = gridDim.x * nby;
  int orig = blockIdx.x * nby + blockIdx.y;
  {
    int q = nwg >> 3, r = nwg & 7;
    int xcd = orig & 7, i = orig >> 3;
    orig = (xcd < r ? xcd * (q + 1) : r * (q + 1) + (xcd - r) * q) + i;
  }
  const int m0 = (orig % nby) * 64, n0 = (orig / nby) * 128;

  const int wr = (w >> 1) * 32, wc = (w & 1) * 64;
  const int lr = lane & 15, lk8 = (lane >> 4) * 8;
  const int lcol = lk8 ^ (((lr >> 1) & 3) << 3);
  const int g4 = (lane >> 4) * 4;
  f32x4 acc[2][4] = {};

  int rB0 = n0 + (t >> 2); if (rB0 > N - 1) rB0 = N - 1;
  int rB1 = n0 + 64 + (t >> 2); if (rB1 > N - 1) rB1 = N - 1;
  const size_t ga  = (size_t)(m0 + (t >> 2)) * K + (((t & 3) ^ ((t >> 3) & 3)) * 8);
  const size_t gb0 = (size_t)rB0 * K + (((t & 3) ^ ((t >> 3) & 3)) * 8);
  const size_t gb1 = (size_t)rB1 * K + (((t & 3) ^ ((t >> 3) & 3)) * 8);

  auto STAGE = [&](int buf, int k0) {
    GLOAD16(A + ga + k0,        &As[buf * 4096 + t * 8]);
    GLOAD16(A + ga + k0 + 32,   &As[buf * 4096 + 2048 + t * 8]);
    GLOAD16(B + gb0 + k0,       &Bs[buf * 8192 + t * 8]);
    GLOAD16(B + gb1 + k0,       &Bs[buf * 8192 + (t + 256) * 8]);
    GLOAD16(B + gb0 + k0 + 32,  &Bs[buf * 8192 + 4096 + t * 8]);
    GLOAD16(B + gb1 + k0 + 32,  &Bs[buf * 8192 + 4096 + (t + 256) * 8]);
  };

  const int nk2 = K / 64;
  STAGE(0, 0);

  for (int tt = 0; tt < nk2; ++tt) {
    const int cur = tt & 1;
    if (tt + 1 < nk2) {
      STAGE(cur ^ 1, (tt + 1) * 64);
      asm volatile("s_waitcnt vmcnt(6)" ::: "memory");
    } else {
      asm volatile("s_waitcnt vmcnt(0)" ::: "memory");
    }
    __builtin_amdgcn_s_barrier();
    __builtin_amdgcn_sched_barrier(0);
    const u16* as_ = &As[cur * 4096];
    const u16* bs_ = &Bs[cur * 8192];
    bf16x8 af[2][2], bf_[2][4];
#pragma unroll
    for (int ks = 0; ks < 2; ++ks) {
#pragma unroll
      for (int i = 0; i < 2; ++i)
        af[ks][i] = *(const bf16x8*)&as_[ks * 2048 + (wr + i * 16 + lr) * 32 + lcol];
#pragma unroll
      for (int j = 0; j < 4; ++j)
        bf_[ks][j] = *(const bf16x8*)&bs_[ks * 4096 + (wc + j * 16 + lr) * 32 + lcol];
    }
#pragma unroll
    for (int ks = 0; ks < 2; ++ks)
#pragma unroll
      for (int i = 0; i < 2; ++i)
#pragma unroll
        for (int j = 0; j < 4; ++j)
          acc[i][j] = __builtin_amdgcn_mfma_f32_16x16x32_bf16(af[ks][i], bf_[ks][j], acc[i][j], 0, 0, 0);
    __builtin_amdgcn_sched_barrier(0);
    __builtin_amdgcn_s_barrier();
  }

#pragma unroll
  for (int i = 0; i < 2; ++i) {
    const int row = m0 + wr + i * 16 + g4;
#pragma unroll
    for (int j = 0; j < 4; ++j) {
      const int col = n0 + wc + j * 16 + lr;
      if (col < N) {
        const float bb = bias[col];
#pragma unroll
        for (int r = 0; r < 4; ++r)
          C[(size_t)(row + r) * N + col] = acc[i][j][r] + bb;
      }
    }
  }
}

// ---------------- fused attention + ow-conversion tail blocks ----------------
// attn blocks (blockIdx.x < ATTN_BLOCKS) dispatched first; 11520 conv blocks
// backfill CU slots and convert out_w (f32->bf16) overlapped with attention
// (attn is MFMA/latency-bound, conv is BW-bound -> orthogonal resources).
__global__ __launch_bounds__(256) void attn2(
    const u16* __restrict__ Q, const u16* __restrict__ Kb, const u16* __restrict__ Vt,
    const float* __restrict__ sinks, u16* __restrict__ O,
    const float* __restrict__ ow_src, u16* __restrict__ ow_dst) {
  const int b = blockIdx.x;
  if (b >= ATTN_BLOCKS) {
    long idx = (long)(b - ATTN_BLOCKS) * 256 + threadIdx.x;  // < 2880*4096/4 exactly
    float4 v = *(const float4*)&ow_src[idx * 4];
    ushort4 h;
    h.x = f2bf(v.x); h.y = f2bf(v.y); h.z = f2bf(v.z); h.w = f2bf(v.w);
    *(ushort4*)&ow_dst[idx * 4] = h;
    return;
  }
  const int h = b & 63;
  const int kh = h >> 3;
  const int wid = threadIdx.x >> 6;
  const int lane = threadIdx.x & 63;
  const int q0 = (b >> 6) * 128 + wid * 32;
  const int lr = lane & 15;
  const int g = lane >> 4;

  bf16x8 bq[2][2];
#pragma unroll
  for (int qf = 0; qf < 2; ++qf)
#pragma unroll
    for (int kc = 0; kc < 2; ++kc)
      bq[qf][kc] = *(const bf16x8*)&Q[(size_t)(q0 + qf * 16 + lr) * QDIM + h * HD + kc * 32 + g * 8];

  f32x4 o[2][4] = {};
  float m_s[2] = {-1e30f, -1e30f};
  float l_s[2] = {0.f, 0.f};

  int js = q0 - 128; if (js < 0) js = 0;

  for (int j0 = js; j0 <= q0; j0 += 32) {
    bf16x8 ak[2][2];
#pragma unroll
    for (int jf = 0; jf < 2; ++jf)
#pragma unroll
      for (int kc = 0; kc < 2; ++kc)
        ak[jf][kc] = *(const bf16x8*)&Kb[(size_t)(j0 + jf * 16 + lr) * KVDIM + kh * HD + kc * 32 + g * 8];

    f32x4 st[2][2] = {};
#pragma unroll
    for (int jf = 0; jf < 2; ++jf)
#pragma unroll
      for (int qf = 0; qf < 2; ++qf) {
        st[jf][qf] = __builtin_amdgcn_mfma_f32_16x16x32_bf16(ak[jf][0], bq[qf][0], st[jf][qf], 0, 0, 0);
        st[jf][qf] = __builtin_amdgcn_mfma_f32_16x16x32_bf16(ak[jf][1], bq[qf][1], st[jf][qf], 0, 0, 0);
      }

    float pv[2][2][4];
    float tmax[2] = {-1e30f, -1e30f};
#pragma unroll
    for (int jf = 0; jf < 2; ++jf)
#pragma unroll
      for (int qf = 0; qf < 2; ++qf)
#pragma unroll
        for (int r = 0; r < 4; ++r) {
          int jv = j0 + jf * 16 + 4 * g + r;
          int qq = q0 + qf * 16 + lr;
          float sc = st[jf][qf][r];
          bool ok = (jv <= qq) && (qq - jv < WIN);
          sc = ok ? sc : -1e30f;
          pv[jf][qf][r] = sc;
          tmax[qf] = fmaxf(tmax[qf], sc);
        }
#pragma unroll
    for (int qf = 0; qf < 2; ++qf) {
      float tm = tmax[qf];
      tm = fmaxf(tm, __shfl_xor(tm, 16));
      tm = fmaxf(tm, __shfl_xor(tm, 32));
      const float mo = m_s[qf];
      const float mn = fmaxf(mo, tm);
      const float esc = __expf(mo - mn);
      float ps = 0.f;
#pragma unroll
      for (int jf = 0; jf < 2; ++jf)
#pragma unroll
        for (int r = 0; r < 4; ++r) {
          float sv = pv[jf][qf][r];
          float e = __expf(sv - mn);
          e = (sv <= -1e29f) ? 0.f : e;
          pv[jf][qf][r] = e;
          ps += e;
        }
      ps += __shfl_xor(ps, 16);
      ps += __shfl_xor(ps, 32);
      l_s[qf] = l_s[qf] * esc + ps;
      m_s[qf] = mn;
#pragma unroll
      for (int df = 0; df < 4; ++df) o[qf][df] *= esc;
    }

    bf16x8 pb[2];
    const int srcA = lr + ((g & 1) ? 32 : 0);
    const int srcB = srcA + 16;
    const bool hi_half = (g >= 2);
#pragma unroll
    for (int qf = 0; qf < 2; ++qf) {
      u32 w0a = pk2bf(pv[0][qf][0], pv[0][qf][1]);
      u32 w1a = pk2bf(pv[0][qf][2], pv[0][qf][3]);
      u32 w0b = pk2bf(pv[1][qf][0], pv[1][qf][1]);
      u32 w1b = pk2bf(pv[1][qf][2], pv[1][qf][3]);
      u32 a0 = (u32)__shfl((int)w0a, srcA, 64);
      u32 a1 = (u32)__shfl((int)w1a, srcA, 64);
      u32 a2 = (u32)__shfl((int)w0a, srcB, 64);
      u32 a3 = (u32)__shfl((int)w1a, srcB, 64);
      u32 b0 = (u32)__shfl((int)w0b, srcA, 64);
      u32 b1 = (u32)__shfl((int)w1b, srcA, 64);
      u32 b2 = (u32)__shfl((int)w0b, srcB, 64);
      u32 b3 = (u32)__shfl((int)w1b, srcB, 64);
      union { u32 d[4]; bf16x8 v; } u_;
      u_.d[0] = hi_half ? b0 : a0;
      u_.d[1] = hi_half ? b1 : a1;
      u_.d[2] = hi_half ? b2 : a2;
      u_.d[3] = hi_half ? b3 : a3;
      pb[qf] = u_.v;
    }

    bf16x8 av[4];
#pragma unroll
    for (int df = 0; df < 4; ++df)
      av[df] = *(const bf16x8*)&Vt[((size_t)kh * HD + df * 16 + lr) * S_LEN + j0 + g * 8];

#pragma unroll
    for (int qf = 0; qf < 2; ++qf)
#pragma unroll
      for (int df = 0; df < 4; ++df)
        o[qf][df] = __builtin_amdgcn_mfma_f32_16x16x32_bf16(av[df], pb[qf], o[qf][df], 0, 0, 0);
  }

  const float snk = sinks[h];
#pragma unroll
  for (int qf = 0; qf < 2; ++qf) {
    const float mo = m_s[qf];
    const float Mx = fmaxf(mo, snk);
    const float den = l_s[qf] * __expf(mo - Mx) + __expf(snk - Mx);
    const float osc = __expf(mo - Mx) / den;
    const int row = q0 + qf * 16 + lr;
#pragma unroll
    for (int df = 0; df < 4; ++df) {
      ushort4 pk;
      pk.x = f2bf(o[qf][df][0] * osc);
      pk.y = f2bf(o[qf][df][1] * osc);
      pk.z = f2bf(o[qf][df][2] * osc);
      pk.w = f2bf(o[qf][df][3] * osc);
      *(ushort4*)&O[(size_t)row * QDIM + h * HD + df * 16 + 4 * g] = pk;
    }
  }
}

// ---------------- launcher ----------------
extern "C" void kernel_launch(void* const* d_in, const int* in_sizes, int n_in,
                              void* d_out, int out_size, void* d_ws, size_t ws_size,
                              hipStream_t stream) {
  const float* x      = (const float*)d_in[0];
  const float* sinks  = (const float*)d_in[1];
  const float* norm_w = (const float*)d_in[2];
  const float* qkv_w  = (const float*)d_in[3];
  const float* qkv_b  = (const float*)d_in[4];
  const float* out_w  = (const float*)d_in[5];
  const float* out_b  = (const float*)d_in[6];
  float* out = (float*)d_out;

  char* ws = (char*)d_ws;
  size_t off = 0;
  auto take = [&](size_t bytes) -> void* {
    void* r = ws + off;
    off += (bytes + 255) & ~(size_t)255;
    return r;
  };
  float* cosT = (float*)take((size_t)S_LEN * 32 * 4);
  float* sinT = (float*)take((size_t)S_LEN * 32 * 4);
  u16* th  = (u16*)take((size_t)S_LEN * DIM * 2);
  u16* wh  = (u16*)take((size_t)QKV_N * DIM * 2);
  u16* ow  = (u16*)take((size_t)DIM * QDIM * 2);
  u16* Qb  = (u16*)take((size_t)S_LEN * QDIM * 2);
  u16* Kb  = (u16*)take((size_t)S_LEN * KVDIM * 2);
  u16* Vt  = (u16*)take((size_t)S_LEN * KVDIM * 2);
  u16* Ab  = (u16*)take((size_t)S_LEN * QDIM * 2);

  pre_all<<<CONV1_BLOCKS + RMS_BLOCKS + ROPE_BLOCKS, 256, 0, stream>>>(
      x, norm_w, th, qkv_w, wh, cosT, sinT);
  gemm_rope<<<dim3(QKV_N / 128, S_LEN / 128), 256, 0, stream>>>(
      th, wh, qkv_b, cosT, sinT, Qb, Kb, Vt);
  attn2<<<ATTN_BLOCKS + OWCONV_BLOCKS, 256, 0, stream>>>(
      Qb, Kb, Vt, sinks, Ab, out_w, ow);
  gemm_bt<<<dim3((DIM + 127) / 128, S_LEN / 64), 256, 0, stream>>>(
      Ab, ow, out_b, out, S_LEN, DIM, QDIM);
}